// Round 1
// baseline (4464.652 us; speedup 1.0000x reference)
//
#include <hip/hip_runtime.h>
#include <hip/hip_bf16.h>
#include <math.h>

// Problem: B=16, N=512, D=256, H=8, L=4, DFF=1024, K=128, DH=32
#define BB 16
#define NN 512
#define DD 256
#define HH 8
#define LL 4
#define DFF 1024
#define KSEL 128
#define DH 32

// ---------------- workspace layout (float offsets) ----------------
// x:    [0,        2097152)   8192*256
// h:    [2097152,  4194304)
// q:    [4194304,  6291456)
// k:    [6291456,  8388608)
// v:    [8388608, 10485760)
// attn: [10485760,12582912)
// ffn_t overlays q..attn: [4194304, 12582912)  (8192*1024)
// s:    [12582912,12591104)  16*512
// idx:  [12591104,12593152)  16*128 ints
static const size_t X_OFF    = 0;
static const size_t H_OFF    = 2097152;
static const size_t Q_OFF    = 4194304;
static const size_t K_OFF    = 6291456;
static const size_t V_OFF    = 8388608;
static const size_t ATTN_OFF = 10485760;
static const size_t FFN_OFF  = 4194304;
static const size_t S_OFF    = 12582912;
static const size_t IDX_OFF  = 12591104;

// ---------------- helpers ----------------
__device__ __forceinline__ float gelu_f(float x) {
  float x3 = x * x * x;
  return 0.5f * x * (1.f + tanhf(0.7978845608028654f * (x + 0.044715f * x3)));
}

// block of 256 threads (4 waves)
__device__ __forceinline__ float blk_sum_256(float v, float* stmp) {
  #pragma unroll
  for (int o = 32; o > 0; o >>= 1) v += __shfl_down(v, o, 64);
  if ((threadIdx.x & 63) == 0) stmp[threadIdx.x >> 6] = v;
  __syncthreads();
  if (threadIdx.x == 0) stmp[0] = stmp[0] + stmp[1] + stmp[2] + stmp[3];
  __syncthreads();
  float r = stmp[0];
  __syncthreads();
  return r;
}

// block of 512 threads (8 waves)
__device__ __forceinline__ float blk_max_512(float v, float* stmp) {
  #pragma unroll
  for (int o = 32; o > 0; o >>= 1) v = fmaxf(v, __shfl_down(v, o, 64));
  if ((threadIdx.x & 63) == 0) stmp[threadIdx.x >> 6] = v;
  __syncthreads();
  if (threadIdx.x == 0) {
    float m = stmp[0];
    #pragma unroll
    for (int i = 1; i < 8; ++i) m = fmaxf(m, stmp[i]);
    stmp[0] = m;
  }
  __syncthreads();
  float r = stmp[0];
  __syncthreads();
  return r;
}

__device__ __forceinline__ float blk_sum_512(float v, float* stmp) {
  #pragma unroll
  for (int o = 32; o > 0; o >>= 1) v += __shfl_down(v, o, 64);
  if ((threadIdx.x & 63) == 0) stmp[threadIdx.x >> 6] = v;
  __syncthreads();
  if (threadIdx.x == 0) {
    float m = stmp[0];
    #pragma unroll
    for (int i = 1; i < 8; ++i) m += stmp[i];
    stmp[0] = m;
  }
  __syncthreads();
  float r = stmp[0];
  __syncthreads();
  return r;
}

// ---------------- kernels ----------------
__global__ void copy_kernel(const float4* __restrict__ src, float4* __restrict__ dst, int n) {
  int i = blockIdx.x * blockDim.x + threadIdx.x;
  if (i < n) dst[i] = src[i];
}

__global__ __launch_bounds__(256) void ln_kernel(const float* __restrict__ in,
                                                 const float* __restrict__ g,
                                                 const float* __restrict__ bb,
                                                 float* __restrict__ out) {
  __shared__ float stmp[4];
  size_t row = blockIdx.x;
  int d = threadIdx.x;
  float v = in[row * DD + d];
  float mu = blk_sum_256(v, stmp) * (1.0f / DD);
  float diff = v - mu;
  float var = blk_sum_256(diff * diff, stmp) * (1.0f / DD);
  out[row * DD + d] = diff * rsqrtf(var + 1e-6f) * g[d] + bb[d];
}

// C[M,N] = op(A[M,K] @ B[K,N]); MODE 0: plain, 1: Res + AB, 2: gelu(AB)
template <int MODE>
__global__ __launch_bounds__(256) void gemm_kernel(const float* __restrict__ A,
                                                   const float* __restrict__ B,
                                                   const float* __restrict__ Res,
                                                   float* __restrict__ C,
                                                   int M, int N, int Kd) {
  __shared__ float sA[16][65];
  __shared__ float sB[16][65];
  int tid = threadIdx.x;
  int bm = blockIdx.y << 6, bn = blockIdx.x << 6;
  int tx = tid & 15, ty = tid >> 4;
  float acc[4][4] = {};
  for (int k0 = 0; k0 < Kd; k0 += 16) {
    #pragma unroll
    for (int i = 0; i < 4; ++i) {
      int idx = (i << 8) + tid;
      int am = idx >> 4, ak = idx & 15;
      sA[ak][am] = A[(size_t)(bm + am) * Kd + k0 + ak];
      int bk = idx >> 6, bnn = idx & 63;
      sB[bk][bnn] = B[(size_t)(k0 + bk) * N + bn + bnn];
    }
    __syncthreads();
    #pragma unroll
    for (int kk = 0; kk < 16; ++kk) {
      float a0 = sA[kk][ty * 4 + 0], a1 = sA[kk][ty * 4 + 1];
      float a2 = sA[kk][ty * 4 + 2], a3 = sA[kk][ty * 4 + 3];
      float b0 = sB[kk][tx * 4 + 0], b1 = sB[kk][tx * 4 + 1];
      float b2 = sB[kk][tx * 4 + 2], b3 = sB[kk][tx * 4 + 3];
      acc[0][0] = fmaf(a0, b0, acc[0][0]); acc[0][1] = fmaf(a0, b1, acc[0][1]);
      acc[0][2] = fmaf(a0, b2, acc[0][2]); acc[0][3] = fmaf(a0, b3, acc[0][3]);
      acc[1][0] = fmaf(a1, b0, acc[1][0]); acc[1][1] = fmaf(a1, b1, acc[1][1]);
      acc[1][2] = fmaf(a1, b2, acc[1][2]); acc[1][3] = fmaf(a1, b3, acc[1][3]);
      acc[2][0] = fmaf(a2, b0, acc[2][0]); acc[2][1] = fmaf(a2, b1, acc[2][1]);
      acc[2][2] = fmaf(a2, b2, acc[2][2]); acc[2][3] = fmaf(a2, b3, acc[2][3]);
      acc[3][0] = fmaf(a3, b0, acc[3][0]); acc[3][1] = fmaf(a3, b1, acc[3][1]);
      acc[3][2] = fmaf(a3, b2, acc[3][2]); acc[3][3] = fmaf(a3, b3, acc[3][3]);
    }
    __syncthreads();
  }
  #pragma unroll
  for (int i = 0; i < 4; ++i) {
    int m = bm + ty * 4 + i;
    #pragma unroll
    for (int j = 0; j < 4; ++j) {
      int n = bn + tx * 4 + j;
      float vv = acc[i][j];
      if (MODE == 1) vv += Res[(size_t)m * N + n];
      if (MODE == 2) vv = gelu_f(vv);
      C[(size_t)m * N + n] = vv;
    }
  }
}

// one block per (b, h, q): 512 threads, thread j handles key j
__global__ __launch_bounds__(512) void attn_kernel(const float* __restrict__ qg,
                                                   const float* __restrict__ kg,
                                                   const float* __restrict__ vg,
                                                   const float* __restrict__ dist,
                                                   float* __restrict__ outg,
                                                   float* __restrict__ s_acc,
                                                   int accum) {
  __shared__ float sQ[32];
  __shared__ float sP[512];
  __shared__ float sOut[16][32];
  __shared__ float sTmp[8];
  const int qi = blockIdx.x, h = blockIdx.y, b = blockIdx.z;
  const int tid = threadIdx.x;
  const size_t rowq = (size_t)b * NN + qi;
  if (tid < 32) sQ[tid] = qg[rowq * DD + h * DH + tid];
  __syncthreads();
  const float* kp = kg + ((size_t)b * NN + tid) * DD + h * DH;
  float dot = 0.f;
  #pragma unroll
  for (int d0 = 0; d0 < DH; d0 += 4) {
    float4 kv = *(const float4*)(kp + d0);
    dot = fmaf(sQ[d0 + 0], kv.x, dot);
    dot = fmaf(sQ[d0 + 1], kv.y, dot);
    dot = fmaf(sQ[d0 + 2], kv.z, dot);
    dot = fmaf(sQ[d0 + 3], kv.w, dot);
  }
  float logit = dot * 0.17677669529663687f - dist[rowq * NN + tid];
  float mx = blk_max_512(logit, sTmp);
  float e = expf(logit - mx);
  float sum = blk_sum_512(e, sTmp);
  float p = e / sum;
  if (accum) atomicAdd(&s_acc[b * NN + tid], p * (1.0f / HH));
  sP[tid] = p;
  __syncthreads();
  const int dh = tid & 31, grp = tid >> 5;
  const float* vp = vg + ((size_t)b * NN + grp * 32) * DD + h * DH + dh;
  float acc = 0.f;
  #pragma unroll 8
  for (int j = 0; j < 32; ++j) acc = fmaf(sP[grp * 32 + j], vp[(size_t)j * DD], acc);
  sOut[grp][dh] = acc;
  __syncthreads();
  if (tid < 32) {
    float r = 0.f;
    #pragma unroll
    for (int g2 = 0; g2 < 16; ++g2) r += sOut[g2][tid];
    outg[rowq * DD + h * DH + tid] = r;
  }
}

// one block per batch: sequential farthest-point sampling (matches jax ref)
__global__ __launch_bounds__(512) void afps_kernel(const float* __restrict__ dist,
                                                   const float* __restrict__ s,
                                                   int* __restrict__ idx_out) {
  __shared__ float sVal[512];
  __shared__ int sIdx[512];
  __shared__ int sel[512];
  const int b = blockIdx.x;
  const int tid = threadIdx.x;
  const float* db = dist + (size_t)b * NN * NN;
  // max over dist[b]
  float m = 0.f;
  for (int i = tid; i < NN * NN; i += 512) m = fmaxf(m, db[i]);
  sVal[tid] = m;
  __syncthreads();
  for (int st = 256; st > 0; st >>= 1) {
    if (tid < st) sVal[tid] = fmaxf(sVal[tid], sVal[tid + st]);
    __syncthreads();
  }
  float maxd = sVal[0];
  __syncthreads();
  // max over s[b]
  sVal[tid] = s[b * NN + tid];
  __syncthreads();
  for (int st = 256; st > 0; st >>= 1) {
    if (tid < st) sVal[tid] = fmaxf(sVal[tid], sVal[tid + st]);
    __syncthreads();
  }
  float maxs = sVal[0];
  __syncthreads();

  float invmaxd = 1.0f / maxd;
  float sn = (s[b * NN + tid] / maxs) * 0.1f;
  float mind = db[(size_t)tid * NN + 0] * invmaxd + sn;
  sel[tid] = (tid == 0) ? 1 : 0;
  if (tid == 0) idx_out[b * KSEL + 0] = 0;
  __syncthreads();
  for (int it = 1; it < KSEL; ++it) {
    sVal[tid] = sel[tid] ? -INFINITY : mind;
    sIdx[tid] = tid;
    __syncthreads();
    for (int st = 256; st > 0; st >>= 1) {
      if (tid < st) {
        float a = sVal[tid], c = sVal[tid + st];
        int ia = sIdx[tid], ic = sIdx[tid + st];
        if (c > a || (c == a && ic < ia)) { sVal[tid] = c; sIdx[tid] = ic; }
      }
      __syncthreads();
    }
    int nw = sIdx[0];
    __syncthreads();
    if (tid == 0) idx_out[b * KSEL + it] = nw;
    if (tid == nw) sel[tid] = 1;
    mind = fminf(mind, db[(size_t)tid * NN + nw] * invmaxd + sn);
    __syncthreads();
  }
}

// one block per batch: gather K rows, mean, LN -> out
__global__ __launch_bounds__(256) void pool_ln_kernel(const float* __restrict__ x,
                                                      const int* __restrict__ idx,
                                                      const float* __restrict__ gamma,
                                                      const float* __restrict__ beta,
                                                      float* __restrict__ out) {
  __shared__ float stmp[4];
  __shared__ int sIdx[KSEL];
  const int b = blockIdx.x;
  const int d = threadIdx.x;
  if (d < KSEL) sIdx[d] = idx[b * KSEL + d];
  __syncthreads();
  float acc = 0.f;
  #pragma unroll 4
  for (int kk = 0; kk < KSEL; ++kk)
    acc += x[((size_t)b * NN + sIdx[kk]) * DD + d];
  float p = acc * (1.0f / KSEL);
  float mu = blk_sum_256(p, stmp) * (1.0f / DD);
  float diff = p - mu;
  float var = blk_sum_256(diff * diff, stmp) * (1.0f / DD);
  out[b * DD + d] = diff * rsqrtf(var + 1e-6f) * gamma[d] + beta[d];
}

// ---------------- launcher ----------------
extern "C" void kernel_launch(void* const* d_in, const int* in_sizes, int n_in,
                              void* d_out, int out_size, void* d_ws, size_t ws_size,
                              hipStream_t stream) {
  (void)in_sizes; (void)n_in; (void)out_size; (void)ws_size;
  const float* x_in  = (const float*)d_in[0];
  const float* dist  = (const float*)d_in[1];
  // d_in[2] = mask, all true -> unused
  const float* Wq    = (const float*)d_in[3];
  const float* Wk    = (const float*)d_in[4];
  const float* Wv    = (const float*)d_in[5];
  const float* Wo    = (const float*)d_in[6];
  const float* W1    = (const float*)d_in[7];
  const float* W2    = (const float*)d_in[8];
  const float* ln1_g = (const float*)d_in[9];
  const float* ln1_b = (const float*)d_in[10];
  const float* ln2_g = (const float*)d_in[11];
  const float* ln2_b = (const float*)d_in[12];
  const float* gamma = (const float*)d_in[13];
  const float* beta  = (const float*)d_in[14];

  float* ws   = (float*)d_ws;
  float* x    = ws + X_OFF;
  float* h    = ws + H_OFF;
  float* qb   = ws + Q_OFF;
  float* kb   = ws + K_OFF;
  float* vb   = ws + V_OFF;
  float* attn = ws + ATTN_OFF;
  float* ffn  = ws + FFN_OFF;
  float* sbuf = ws + S_OFF;
  int*   idxb = (int*)(ws + IDX_OFF);
  float* out  = (float*)d_out;

  // x_ws = x_in
  copy_kernel<<<2048, 256, 0, stream>>>((const float4*)x_in, (float4*)x, 524288);
  hipMemsetAsync(sbuf, 0, BB * NN * sizeof(float), stream);

  const int M = BB * NN;  // 8192
  dim3 g1(DD / 64, M / 64);    // (4,128)
  dim3 g2(DFF / 64, M / 64);   // (16,128)
  dim3 ga(NN, HH, BB);

  for (int l = 0; l < LL; ++l) {
    ln_kernel<<<M, 256, 0, stream>>>(x, ln1_g + l * DD, ln1_b + l * DD, h);
    gemm_kernel<0><<<g1, 256, 0, stream>>>(h, Wq + (size_t)l * DD * DD, nullptr, qb, M, DD, DD);
    gemm_kernel<0><<<g1, 256, 0, stream>>>(h, Wk + (size_t)l * DD * DD, nullptr, kb, M, DD, DD);
    gemm_kernel<0><<<g1, 256, 0, stream>>>(h, Wv + (size_t)l * DD * DD, nullptr, vb, M, DD, DD);
    attn_kernel<<<ga, 512, 0, stream>>>(qb, kb, vb, dist, attn, sbuf, (l == LL - 1) ? 1 : 0);
    gemm_kernel<1><<<g1, 256, 0, stream>>>(attn, Wo + (size_t)l * DD * DD, x, x, M, DD, DD);
    ln_kernel<<<M, 256, 0, stream>>>(x, ln2_g + l * DD, ln2_b + l * DD, h);
    gemm_kernel<2><<<g2, 256, 0, stream>>>(h, W1 + (size_t)l * DD * DFF, nullptr, ffn, M, DFF, DD);
    gemm_kernel<1><<<g1, 256, 0, stream>>>(ffn, W2 + (size_t)l * DD * DFF, x, x, M, DD, DFF);
  }
  afps_kernel<<<BB, 512, 0, stream>>>(dist, sbuf, idxb);
  pool_ln_kernel<<<BB, 256, 0, stream>>>(x, idxb, gamma, beta, out);
}

// Round 2
// 4446.354 us; speedup vs baseline: 1.0041x; 1.0041x over previous
//
#include <hip/hip_runtime.h>
#include <hip/hip_bf16.h>
#include <math.h>

// Problem: B=16, N=512, D=256, H=8, L=4, DFF=1024, K=128, DH=32
#define BB 16
#define NN 512
#define DD 256
#define HH 8
#define LL 4
#define DFF 1024
#define KSEL 128
#define DH 32

// ---------------- workspace layout (float offsets) ----------------
static const size_t X_OFF    = 0;
static const size_t H_OFF    = 2097152;
static const size_t Q_OFF    = 4194304;
static const size_t K_OFF    = 6291456;
static const size_t V_OFF    = 8388608;
static const size_t ATTN_OFF = 10485760;
static const size_t FFN_OFF  = 4194304;
static const size_t S_OFF    = 12582912;
static const size_t IDX_OFF  = 12591104;

// ---------------- helpers ----------------
__device__ __forceinline__ float gelu_f(float x) {
  float x3 = x * x * x;
  return 0.5f * x * (1.f + tanhf(0.7978845608028654f * (x + 0.044715f * x3)));
}

__device__ __forceinline__ float blk_sum_256(float v, float* stmp) {
  #pragma unroll
  for (int o = 32; o > 0; o >>= 1) v += __shfl_down(v, o, 64);
  if ((threadIdx.x & 63) == 0) stmp[threadIdx.x >> 6] = v;
  __syncthreads();
  if (threadIdx.x == 0) stmp[0] = stmp[0] + stmp[1] + stmp[2] + stmp[3];
  __syncthreads();
  float r = stmp[0];
  __syncthreads();
  return r;
}

// ---------------- kernels ----------------
__global__ void copy_kernel(const float4* __restrict__ src, float4* __restrict__ dst, int n) {
  int i = blockIdx.x * blockDim.x + threadIdx.x;
  if (i < n) dst[i] = src[i];
}

__global__ __launch_bounds__(256) void ln_kernel(const float* __restrict__ in,
                                                 const float* __restrict__ g,
                                                 const float* __restrict__ bb,
                                                 float* __restrict__ out) {
  __shared__ float stmp[4];
  size_t row = blockIdx.x;
  int d = threadIdx.x;
  float v = in[row * DD + d];
  float mu = blk_sum_256(v, stmp) * (1.0f / DD);
  float diff = v - mu;
  float var = blk_sum_256(diff * diff, stmp) * (1.0f / DD);
  out[row * DD + d] = diff * rsqrtf(var + 1e-6f) * g[d] + bb[d];
}

// C[M,N] = op(A[M,K] @ B[K,N]); MODE 0: plain, 1: Res + AB, 2: gelu(AB)
template <int MODE>
__global__ __launch_bounds__(256) void gemm_kernel(const float* __restrict__ A,
                                                   const float* __restrict__ B,
                                                   const float* __restrict__ Res,
                                                   float* __restrict__ C,
                                                   int M, int N, int Kd) {
  __shared__ float sA[16][65];
  __shared__ float sB[16][65];
  int tid = threadIdx.x;
  int bm = blockIdx.y << 6, bn = blockIdx.x << 6;
  int tx = tid & 15, ty = tid >> 4;
  float acc[4][4] = {};
  for (int k0 = 0; k0 < Kd; k0 += 16) {
    #pragma unroll
    for (int i = 0; i < 4; ++i) {
      int idx = (i << 8) + tid;
      int am = idx >> 4, ak = idx & 15;
      sA[ak][am] = A[(size_t)(bm + am) * Kd + k0 + ak];
      int bk = idx >> 6, bnn = idx & 63;
      sB[bk][bnn] = B[(size_t)(k0 + bk) * N + bn + bnn];
    }
    __syncthreads();
    #pragma unroll
    for (int kk = 0; kk < 16; ++kk) {
      float a0 = sA[kk][ty * 4 + 0], a1 = sA[kk][ty * 4 + 1];
      float a2 = sA[kk][ty * 4 + 2], a3 = sA[kk][ty * 4 + 3];
      float b0 = sB[kk][tx * 4 + 0], b1 = sB[kk][tx * 4 + 1];
      float b2 = sB[kk][tx * 4 + 2], b3 = sB[kk][tx * 4 + 3];
      acc[0][0] = fmaf(a0, b0, acc[0][0]); acc[0][1] = fmaf(a0, b1, acc[0][1]);
      acc[0][2] = fmaf(a0, b2, acc[0][2]); acc[0][3] = fmaf(a0, b3, acc[0][3]);
      acc[1][0] = fmaf(a1, b0, acc[1][0]); acc[1][1] = fmaf(a1, b1, acc[1][1]);
      acc[1][2] = fmaf(a1, b2, acc[1][2]); acc[1][3] = fmaf(a1, b3, acc[1][3]);
      acc[2][0] = fmaf(a2, b0, acc[2][0]); acc[2][1] = fmaf(a2, b1, acc[2][1]);
      acc[2][2] = fmaf(a2, b2, acc[2][2]); acc[2][3] = fmaf(a2, b3, acc[2][3]);
      acc[3][0] = fmaf(a3, b0, acc[3][0]); acc[3][1] = fmaf(a3, b1, acc[3][1]);
      acc[3][2] = fmaf(a3, b2, acc[3][2]); acc[3][3] = fmaf(a3, b3, acc[3][3]);
    }
    __syncthreads();
  }
  #pragma unroll
  for (int i = 0; i < 4; ++i) {
    int m = bm + ty * 4 + i;
    #pragma unroll
    for (int j = 0; j < 4; ++j) {
      int n = bn + tx * 4 + j;
      float vv = acc[i][j];
      if (MODE == 1) vv += Res[(size_t)m * N + n];
      if (MODE == 2) vv = gelu_f(vv);
      C[(size_t)m * N + n] = vv;
    }
  }
}

// Attention: block = 256 threads = 16 queries x 8 heads x 2 dim-halves.
// grid = (N/16, B). All state in registers; online (no-max) softmax.
// Logits are bounded (LN'd inputs, |dot*scale - dist| << 80) so exp() is
// fp32-safe without max subtraction -> identical math to softmax.
__global__ __launch_bounds__(256) void attn_kernel(const float* __restrict__ qg,
                                                   const float* __restrict__ kg,
                                                   const float* __restrict__ vg,
                                                   const float* __restrict__ dist,
                                                   float* __restrict__ outg,
                                                   float* __restrict__ s_acc,
                                                   int accum) {
  const int tid  = threadIdx.x;
  const int qloc = tid >> 4;        // 0..15
  const int h    = (tid >> 1) & 7;  // 0..7
  const int half = tid & 1;         // 0..1
  const int b    = blockIdx.y;
  const int qglob = blockIdx.x * 16 + qloc;
  const size_t rowq = (size_t)b * NN + qglob;
  const int doff = h * DH + half * 16;

  float qreg[16];
  const float* qp = qg + rowq * DD + doff;
  #pragma unroll
  for (int i = 0; i < 4; ++i) {
    float4 t = *(const float4*)(qp + i * 4);
    qreg[i * 4 + 0] = t.x; qreg[i * 4 + 1] = t.y;
    qreg[i * 4 + 2] = t.z; qreg[i * 4 + 3] = t.w;
  }
  const float* distrow = dist + rowq * NN;
  const float* kbase = kg + (size_t)b * NN * DD + doff;
  const float* vbase = vg + (size_t)b * NN * DD + doff;

  float O[16] = {};
  float l = 0.f;
  #pragma unroll 2
  for (int j = 0; j < NN; ++j) {
    const float* kp = kbase + (size_t)j * DD;
    float d0 = 0.f;
    #pragma unroll
    for (int i = 0; i < 4; ++i) {
      float4 kv = *(const float4*)(kp + i * 4);
      d0 = fmaf(qreg[i * 4 + 0], kv.x, d0);
      d0 = fmaf(qreg[i * 4 + 1], kv.y, d0);
      d0 = fmaf(qreg[i * 4 + 2], kv.z, d0);
      d0 = fmaf(qreg[i * 4 + 3], kv.w, d0);
    }
    float dot = d0 + __shfl_xor(d0, 1, 64);
    float logit = fmaf(dot, 0.17677669529663687f, -distrow[j]);
    float e = __expf(logit);
    l += e;
    const float* vp = vbase + (size_t)j * DD;
    #pragma unroll
    for (int i = 0; i < 4; ++i) {
      float4 vv = *(const float4*)(vp + i * 4);
      O[i * 4 + 0] = fmaf(e, vv.x, O[i * 4 + 0]);
      O[i * 4 + 1] = fmaf(e, vv.y, O[i * 4 + 1]);
      O[i * 4 + 2] = fmaf(e, vv.z, O[i * 4 + 2]);
      O[i * 4 + 3] = fmaf(e, vv.w, O[i * 4 + 3]);
    }
  }
  float invl = 1.f / l;
  float* op = outg + rowq * DD + doff;
  #pragma unroll
  for (int i = 0; i < 4; ++i) {
    float4 t;
    t.x = O[i * 4 + 0] * invl; t.y = O[i * 4 + 1] * invl;
    t.z = O[i * 4 + 2] * invl; t.w = O[i * 4 + 3] * invl;
    *(float4*)(op + i * 4) = t;
  }

  // Last layer: accumulate s[b,k] = sum_q mean_h p[q,k] (recompute QK only).
  if (accum) {
    const float sscale = invl * (1.0f / (2.0f * HH));  // both halves counted
    for (int j = 0; j < NN; ++j) {
      const float* kp = kbase + (size_t)j * DD;
      float d0 = 0.f;
      #pragma unroll
      for (int i = 0; i < 4; ++i) {
        float4 kv = *(const float4*)(kp + i * 4);
        d0 = fmaf(qreg[i * 4 + 0], kv.x, d0);
        d0 = fmaf(qreg[i * 4 + 1], kv.y, d0);
        d0 = fmaf(qreg[i * 4 + 2], kv.z, d0);
        d0 = fmaf(qreg[i * 4 + 3], kv.w, d0);
      }
      float dot = d0 + __shfl_xor(d0, 1, 64);
      float logit = fmaf(dot, 0.17677669529663687f, -distrow[j]);
      float p = __expf(logit) * sscale;  // p duplicated across half pair
      // wave-reduce: all 64 lanes target same s_acc[b*NN+j]
      #pragma unroll
      for (int o = 32; o > 0; o >>= 1) p += __shfl_xor(p, o, 64);
      if ((tid & 63) == 0) atomicAdd(&s_acc[b * NN + j], p);
    }
  }
}

// one block per batch: sequential farthest-point sampling (matches jax ref)
__global__ __launch_bounds__(512) void afps_kernel(const float* __restrict__ dist,
                                                   const float* __restrict__ s,
                                                   int* __restrict__ idx_out) {
  __shared__ float sVal[512];
  __shared__ int sIdx[512];
  __shared__ int sel[512];
  const int b = blockIdx.x;
  const int tid = threadIdx.x;
  const float* db = dist + (size_t)b * NN * NN;
  float m = 0.f;
  for (int i = tid; i < NN * NN; i += 512) m = fmaxf(m, db[i]);
  sVal[tid] = m;
  __syncthreads();
  for (int st = 256; st > 0; st >>= 1) {
    if (tid < st) sVal[tid] = fmaxf(sVal[tid], sVal[tid + st]);
    __syncthreads();
  }
  float maxd = sVal[0];
  __syncthreads();
  sVal[tid] = s[b * NN + tid];
  __syncthreads();
  for (int st = 256; st > 0; st >>= 1) {
    if (tid < st) sVal[tid] = fmaxf(sVal[tid], sVal[tid + st]);
    __syncthreads();
  }
  float maxs = sVal[0];
  __syncthreads();

  float invmaxd = 1.0f / maxd;
  float sn = (s[b * NN + tid] / maxs) * 0.1f;
  float mind = db[(size_t)tid * NN + 0] * invmaxd + sn;
  sel[tid] = (tid == 0) ? 1 : 0;
  if (tid == 0) idx_out[b * KSEL + 0] = 0;
  __syncthreads();
  for (int it = 1; it < KSEL; ++it) {
    sVal[tid] = sel[tid] ? -INFINITY : mind;
    sIdx[tid] = tid;
    __syncthreads();
    for (int st = 256; st > 0; st >>= 1) {
      if (tid < st) {
        float a = sVal[tid], c = sVal[tid + st];
        int ia = sIdx[tid], ic = sIdx[tid + st];
        if (c > a || (c == a && ic < ia)) { sVal[tid] = c; sIdx[tid] = ic; }
      }
      __syncthreads();
    }
    int nw = sIdx[0];
    __syncthreads();
    if (tid == 0) idx_out[b * KSEL + it] = nw;
    if (tid == nw) sel[tid] = 1;
    mind = fminf(mind, db[(size_t)tid * NN + nw] * invmaxd + sn);
    __syncthreads();
  }
}

// one block per batch: gather K rows, mean, LN -> out
__global__ __launch_bounds__(256) void pool_ln_kernel(const float* __restrict__ x,
                                                      const int* __restrict__ idx,
                                                      const float* __restrict__ gamma,
                                                      const float* __restrict__ beta,
                                                      float* __restrict__ out) {
  __shared__ float stmp[4];
  __shared__ int sIdx[KSEL];
  const int b = blockIdx.x;
  const int d = threadIdx.x;
  if (d < KSEL) sIdx[d] = idx[b * KSEL + d];
  __syncthreads();
  float acc = 0.f;
  #pragma unroll 4
  for (int kk = 0; kk < KSEL; ++kk)
    acc += x[((size_t)b * NN + sIdx[kk]) * DD + d];
  float p = acc * (1.0f / KSEL);
  float mu = blk_sum_256(p, stmp) * (1.0f / DD);
  float diff = p - mu;
  float var = blk_sum_256(diff * diff, stmp) * (1.0f / DD);
  out[b * DD + d] = diff * rsqrtf(var + 1e-6f) * gamma[d] + beta[d];
}

// ---------------- launcher ----------------
extern "C" void kernel_launch(void* const* d_in, const int* in_sizes, int n_in,
                              void* d_out, int out_size, void* d_ws, size_t ws_size,
                              hipStream_t stream) {
  (void)in_sizes; (void)n_in; (void)out_size; (void)ws_size;
  const float* x_in  = (const float*)d_in[0];
  const float* dist  = (const float*)d_in[1];
  const float* Wq    = (const float*)d_in[3];
  const float* Wk    = (const float*)d_in[4];
  const float* Wv    = (const float*)d_in[5];
  const float* Wo    = (const float*)d_in[6];
  const float* W1    = (const float*)d_in[7];
  const float* W2    = (const float*)d_in[8];
  const float* ln1_g = (const float*)d_in[9];
  const float* ln1_b = (const float*)d_in[10];
  const float* ln2_g = (const float*)d_in[11];
  const float* ln2_b = (const float*)d_in[12];
  const float* gamma = (const float*)d_in[13];
  const float* beta  = (const float*)d_in[14];

  float* ws   = (float*)d_ws;
  float* x    = ws + X_OFF;
  float* h    = ws + H_OFF;
  float* qb   = ws + Q_OFF;
  float* kb   = ws + K_OFF;
  float* vb   = ws + V_OFF;
  float* attn = ws + ATTN_OFF;
  float* ffn  = ws + FFN_OFF;
  float* sbuf = ws + S_OFF;
  int*   idxb = (int*)(ws + IDX_OFF);
  float* out  = (float*)d_out;

  copy_kernel<<<2048, 256, 0, stream>>>((const float4*)x_in, (float4*)x, 524288);
  hipMemsetAsync(sbuf, 0, BB * NN * sizeof(float), stream);

  const int M = BB * NN;  // 8192
  dim3 g1(DD / 64, M / 64);    // (4,128)
  dim3 g2(DFF / 64, M / 64);   // (16,128)
  dim3 ga(NN / 16, BB);        // (32,16)

  for (int l = 0; l < LL; ++l) {
    ln_kernel<<<M, 256, 0, stream>>>(x, ln1_g + l * DD, ln1_b + l * DD, h);
    gemm_kernel<0><<<g1, 256, 0, stream>>>(h, Wq + (size_t)l * DD * DD, nullptr, qb, M, DD, DD);
    gemm_kernel<0><<<g1, 256, 0, stream>>>(h, Wk + (size_t)l * DD * DD, nullptr, kb, M, DD, DD);
    gemm_kernel<0><<<g1, 256, 0, stream>>>(h, Wv + (size_t)l * DD * DD, nullptr, vb, M, DD, DD);
    attn_kernel<<<ga, 256, 0, stream>>>(qb, kb, vb, dist, attn, sbuf, (l == LL - 1) ? 1 : 0);
    gemm_kernel<1><<<g1, 256, 0, stream>>>(attn, Wo + (size_t)l * DD * DD, x, x, M, DD, DD);
    ln_kernel<<<M, 256, 0, stream>>>(x, ln2_g + l * DD, ln2_b + l * DD, h);
    gemm_kernel<2><<<g2, 256, 0, stream>>>(h, W1 + (size_t)l * DD * DFF, nullptr, ffn, M, DFF, DD);
    gemm_kernel<1><<<g1, 256, 0, stream>>>(ffn, W2 + (size_t)l * DD * DFF, x, x, M, DD, DFF);
  }
  afps_kernel<<<BB, 512, 0, stream>>>(dist, sbuf, idxb);
  pool_ln_kernel<<<BB, 256, 0, stream>>>(x, idxb, gamma, beta, out);
}

// Round 4
// 2425.371 us; speedup vs baseline: 1.8408x; 1.8333x over previous
//
#include <hip/hip_runtime.h>
#include <hip/hip_bf16.h>
#include <math.h>

// Problem: B=16, N=512, D=256, H=8, L=4, DFF=1024, K=128, DH=32
#define BB 16
#define NN 512
#define DD 256
#define HH 8
#define LL 4
#define DFF 1024
#define KSEL 128
#define DH 32

// ---------------- workspace layout (float offsets) ----------------
static const size_t X_OFF    = 0;
static const size_t H_OFF    = 2097152;
static const size_t Q_OFF    = 4194304;
static const size_t K_OFF    = 6291456;
static const size_t V_OFF    = 8388608;
static const size_t ATTN_OFF = 10485760;
static const size_t FFN_OFF  = 4194304;
static const size_t S_OFF    = 12582912;
static const size_t IDX_OFF  = 12591104;

// ---------------- helpers ----------------
__device__ __forceinline__ float gelu_f(float x) {
  float x3 = x * x * x;
  return 0.5f * x * (1.f + tanhf(0.7978845608028654f * (x + 0.044715f * x3)));
}

__device__ __forceinline__ float blk_sum_256(float v, float* stmp) {
  #pragma unroll
  for (int o = 32; o > 0; o >>= 1) v += __shfl_down(v, o, 64);
  if ((threadIdx.x & 63) == 0) stmp[threadIdx.x >> 6] = v;
  __syncthreads();
  if (threadIdx.x == 0) stmp[0] = stmp[0] + stmp[1] + stmp[2] + stmp[3];
  __syncthreads();
  float r = stmp[0];
  __syncthreads();
  return r;
}

// ---------------- kernels ----------------
__global__ void copy_kernel(const float4* __restrict__ src, float4* __restrict__ dst, int n) {
  int i = blockIdx.x * blockDim.x + threadIdx.x;
  if (i < n) dst[i] = src[i];
}

__global__ __launch_bounds__(256) void ln_kernel(const float* __restrict__ in,
                                                 const float* __restrict__ g,
                                                 const float* __restrict__ bb,
                                                 float* __restrict__ out) {
  __shared__ float stmp[4];
  size_t row = blockIdx.x;
  int d = threadIdx.x;
  float v = in[row * DD + d];
  float mu = blk_sum_256(v, stmp) * (1.0f / DD);
  float diff = v - mu;
  float var = blk_sum_256(diff * diff, stmp) * (1.0f / DD);
  out[row * DD + d] = diff * rsqrtf(var + 1e-6f) * g[d] + bb[d];
}

// C[M,N] = op(A[M,K] @ B[K,N]); MODE 0: plain, 1: Res + AB, 2: gelu(AB)
template <int MODE>
__global__ __launch_bounds__(256) void gemm_kernel(const float* __restrict__ A,
                                                   const float* __restrict__ B,
                                                   const float* __restrict__ Res,
                                                   float* __restrict__ C,
                                                   int M, int N, int Kd) {
  __shared__ float sA[16][65];
  __shared__ float sB[16][65];
  int tid = threadIdx.x;
  int bm = blockIdx.y << 6, bn = blockIdx.x << 6;
  int tx = tid & 15, ty = tid >> 4;
  float acc[4][4] = {};
  for (int k0 = 0; k0 < Kd; k0 += 16) {
    #pragma unroll
    for (int i = 0; i < 4; ++i) {
      int idx = (i << 8) + tid;
      int am = idx >> 4, ak = idx & 15;
      sA[ak][am] = A[(size_t)(bm + am) * Kd + k0 + ak];
      int bk = idx >> 6, bnn = idx & 63;
      sB[bk][bnn] = B[(size_t)(k0 + bk) * N + bn + bnn];
    }
    __syncthreads();
    #pragma unroll
    for (int kk = 0; kk < 16; ++kk) {
      float a0 = sA[kk][ty * 4 + 0], a1 = sA[kk][ty * 4 + 1];
      float a2 = sA[kk][ty * 4 + 2], a3 = sA[kk][ty * 4 + 3];
      float b0 = sB[kk][tx * 4 + 0], b1 = sB[kk][tx * 4 + 1];
      float b2 = sB[kk][tx * 4 + 2], b3 = sB[kk][tx * 4 + 3];
      acc[0][0] = fmaf(a0, b0, acc[0][0]); acc[0][1] = fmaf(a0, b1, acc[0][1]);
      acc[0][2] = fmaf(a0, b2, acc[0][2]); acc[0][3] = fmaf(a0, b3, acc[0][3]);
      acc[1][0] = fmaf(a1, b0, acc[1][0]); acc[1][1] = fmaf(a1, b1, acc[1][1]);
      acc[1][2] = fmaf(a1, b2, acc[1][2]); acc[1][3] = fmaf(a1, b3, acc[1][3]);
      acc[2][0] = fmaf(a2, b0, acc[2][0]); acc[2][1] = fmaf(a2, b1, acc[2][1]);
      acc[2][2] = fmaf(a2, b2, acc[2][2]); acc[2][3] = fmaf(a2, b3, acc[2][3]);
      acc[3][0] = fmaf(a3, b0, acc[3][0]); acc[3][1] = fmaf(a3, b1, acc[3][1]);
      acc[3][2] = fmaf(a3, b2, acc[3][2]); acc[3][3] = fmaf(a3, b3, acc[3][3]);
    }
    __syncthreads();
  }
  #pragma unroll
  for (int i = 0; i < 4; ++i) {
    int m = bm + ty * 4 + i;
    #pragma unroll
    for (int j = 0; j < 4; ++j) {
      int n = bn + tx * 4 + j;
      float vv = acc[i][j];
      if (MODE == 1) vv += Res[(size_t)m * N + n];
      if (MODE == 2) vv = gelu_f(vv);
      C[(size_t)m * N + n] = vv;
    }
  }
}

// Flash-style attention, fp32, LDS-staged K/V/dist tiles.
// block 256 = 16 q x 8 h x 2 halves(16 dims). grid (N/16, B).
// tid: q = tid & 15, hh = tid >> 4 (h = hh>>1, half = hh&1), doff = hh*16.
// LDS: Ks/Vs 32x256 f32 (32 KB each), Ds 16x33 (32 keys + pad), ~67 KB.
__global__ __launch_bounds__(256) void attn_kernel(const float* __restrict__ qg,
                                                   const float* __restrict__ kg,
                                                   const float* __restrict__ vg,
                                                   const float* __restrict__ dist,
                                                   float* __restrict__ outg,
                                                   float* __restrict__ s_acc,
                                                   int accum) {
  __shared__ float Ks[32 * 256];
  __shared__ float Vs[32 * 256];
  __shared__ float Ds[16][33];   // 32 key cols + 1 pad (bank = (q+j)%32)
  __shared__ float sPart[4][32];

  const int tid = threadIdx.x;
  const int q = tid & 15;
  const int hh = tid >> 4;     // 0..15
  const int doff = hh * 16;    // dim offset within D (h*32 + half*16)
  const int b = blockIdx.y;
  const int qbase = blockIdx.x * 16;
  const int qglob = qbase + q;
  const size_t rowq = (size_t)b * NN + qglob;
  const float scale = 0.17677669529663687f;

  // Q fragment (16 dims) in registers
  float qreg[16];
  {
    const float* qp = qg + rowq * DD + doff;
    #pragma unroll
    for (int i = 0; i < 4; ++i) {
      float4 t = *(const float4*)(qp + i * 4);
      qreg[i * 4 + 0] = t.x; qreg[i * 4 + 1] = t.y;
      qreg[i * 4 + 2] = t.z; qreg[i * 4 + 3] = t.w;
    }
  }

  float O[16] = {};
  float l = 0.f;

  const float4* kg4 = (const float4*)(kg + (size_t)b * NN * DD);
  const float4* vg4 = (const float4*)(vg + (size_t)b * NN * DD);
  const float* distq = dist + ((size_t)b * NN + qbase + (tid >> 3)) * NN;

  for (int t0 = 0; t0 < NN; t0 += 32) {
    // ---- stage K/V tiles (32 rows x 256 f32 = 2048 float4 each) ----
    {
      const int f40 = t0 * 64;  // float4 offset of tile start
      float4* kd = (float4*)Ks;
      float4* vd = (float4*)Vs;
      #pragma unroll
      for (int r = 0; r < 8; ++r) {
        kd[tid + r * 256] = kg4[f40 + tid + r * 256];
        vd[tid + r * 256] = vg4[f40 + tid + r * 256];
      }
      if (tid < 128) {
        int qq = tid >> 3, k4 = tid & 7;
        float4 dv = *(const float4*)(distq + t0 + k4 * 4);
        Ds[qq][k4 * 4 + 0] = dv.x; Ds[qq][k4 * 4 + 1] = dv.y;
        Ds[qq][k4 * 4 + 2] = dv.z; Ds[qq][k4 * 4 + 3] = dv.w;
      }
    }
    __syncthreads();
    // ---- compute over 32 keys from LDS ----
    #pragma unroll 4
    for (int j = 0; j < 32; ++j) {
      const float* kr = Ks + j * 256 + doff;
      float d0 = 0.f, d1 = 0.f;
      #pragma unroll
      for (int i = 0; i < 2; ++i) {
        float4 ka = ((const float4*)kr)[i * 2];
        float4 kb2 = ((const float4*)kr)[i * 2 + 1];
        d0 = fmaf(qreg[i * 8 + 0], ka.x, d0);
        d1 = fmaf(qreg[i * 8 + 1], ka.y, d1);
        d0 = fmaf(qreg[i * 8 + 2], ka.z, d0);
        d1 = fmaf(qreg[i * 8 + 3], ka.w, d1);
        d0 = fmaf(qreg[i * 8 + 4], kb2.x, d0);
        d1 = fmaf(qreg[i * 8 + 5], kb2.y, d1);
        d0 = fmaf(qreg[i * 8 + 6], kb2.z, d0);
        d1 = fmaf(qreg[i * 8 + 7], kb2.w, d1);
      }
      float ds = d0 + d1;
      float dot = ds + __shfl_xor(ds, 16, 64);  // combine halves
      float logit = fmaf(dot, scale, -Ds[q][j]);
      float e = __expf(logit);
      l += e;
      const float* vr = Vs + j * 256 + doff;
      #pragma unroll
      for (int i = 0; i < 4; ++i) {
        float4 vv = ((const float4*)vr)[i];
        O[i * 4 + 0] = fmaf(e, vv.x, O[i * 4 + 0]);
        O[i * 4 + 1] = fmaf(e, vv.y, O[i * 4 + 1]);
        O[i * 4 + 2] = fmaf(e, vv.z, O[i * 4 + 2]);
        O[i * 4 + 3] = fmaf(e, vv.w, O[i * 4 + 3]);
      }
    }
    __syncthreads();
  }

  float invl = 1.f / l;
  {
    float* op = outg + rowq * DD + doff;
    #pragma unroll
    for (int i = 0; i < 4; ++i) {
      float4 t;
      t.x = O[i * 4 + 0] * invl; t.y = O[i * 4 + 1] * invl;
      t.z = O[i * 4 + 2] * invl; t.w = O[i * 4 + 3] * invl;
      *(float4*)(op + i * 4) = t;
    }
  }

  // ---- last layer: accumulate s[b,k] = sum_q mean_h p[q,k] ----
  if (accum) {
    const int waveid = tid >> 6;
    for (int t0 = 0; t0 < NN; t0 += 32) {
      {
        const int f40 = t0 * 64;
        float4* kd = (float4*)Ks;
        #pragma unroll
        for (int r = 0; r < 8; ++r) kd[tid + r * 256] = kg4[f40 + tid + r * 256];
        if (tid < 128) {
          int qq = tid >> 3, k4 = tid & 7;
          float4 dv = *(const float4*)(distq + t0 + k4 * 4);
          Ds[qq][k4 * 4 + 0] = dv.x; Ds[qq][k4 * 4 + 1] = dv.y;
          Ds[qq][k4 * 4 + 2] = dv.z; Ds[qq][k4 * 4 + 3] = dv.w;
        }
      }
      __syncthreads();
      #pragma unroll 2
      for (int j = 0; j < 32; ++j) {
        const float* kr = Ks + j * 256 + doff;
        float d0 = 0.f, d1 = 0.f;
        #pragma unroll
        for (int i = 0; i < 2; ++i) {
          float4 ka = ((const float4*)kr)[i * 2];
          float4 kb2 = ((const float4*)kr)[i * 2 + 1];
          d0 = fmaf(qreg[i * 8 + 0], ka.x, d0);
          d1 = fmaf(qreg[i * 8 + 1], ka.y, d1);
          d0 = fmaf(qreg[i * 8 + 2], ka.z, d0);
          d1 = fmaf(qreg[i * 8 + 3], ka.w, d1);
          d0 = fmaf(qreg[i * 8 + 4], kb2.x, d0);
          d1 = fmaf(qreg[i * 8 + 5], kb2.y, d1);
          d0 = fmaf(qreg[i * 8 + 6], kb2.z, d0);
          d1 = fmaf(qreg[i * 8 + 7], kb2.w, d1);
        }
        float ds = d0 + d1;
        float dot = ds + __shfl_xor(ds, 16, 64);
        float p = __expf(fmaf(dot, scale, -Ds[q][j])) * invl;
        #pragma unroll
        for (int o = 32; o > 0; o >>= 1) p += __shfl_xor(p, o, 64);
        if ((tid & 63) == 0) sPart[waveid][j] = p;
      }
      __syncthreads();
      if (tid < 32) {
        float sv = (sPart[0][tid] + sPart[1][tid] + sPart[2][tid] + sPart[3][tid]) * (1.0f / 16.0f);
        atomicAdd(&s_acc[b * NN + t0 + tid], sv);
      }
      __syncthreads();
    }
  }
}

// one block per batch: sequential farthest-point sampling (matches jax ref)
__global__ __launch_bounds__(512) void afps_kernel(const float* __restrict__ dist,
                                                   const float* __restrict__ s,
                                                   int* __restrict__ idx_out) {
  __shared__ float sVal[512];
  __shared__ int sIdx[512];
  __shared__ int sel[512];
  const int b = blockIdx.x;
  const int tid = threadIdx.x;
  const float* db = dist + (size_t)b * NN * NN;
  float m = 0.f;
  for (int i = tid; i < NN * NN; i += 512) m = fmaxf(m, db[i]);
  sVal[tid] = m;
  __syncthreads();
  for (int st = 256; st > 0; st >>= 1) {
    if (tid < st) sVal[tid] = fmaxf(sVal[tid], sVal[tid + st]);
    __syncthreads();
  }
  float maxd = sVal[0];
  __syncthreads();
  sVal[tid] = s[b * NN + tid];
  __syncthreads();
  for (int st = 256; st > 0; st >>= 1) {
    if (tid < st) sVal[tid] = fmaxf(sVal[tid], sVal[tid + st]);
    __syncthreads();
  }
  float maxs = sVal[0];
  __syncthreads();

  float invmaxd = 1.0f / maxd;
  float sn = (s[b * NN + tid] / maxs) * 0.1f;
  float mind = db[(size_t)tid * NN + 0] * invmaxd + sn;
  sel[tid] = (tid == 0) ? 1 : 0;
  if (tid == 0) idx_out[b * KSEL + 0] = 0;
  __syncthreads();
  for (int it = 1; it < KSEL; ++it) {
    sVal[tid] = sel[tid] ? -INFINITY : mind;
    sIdx[tid] = tid;
    __syncthreads();
    for (int st = 256; st > 0; st >>= 1) {
      if (tid < st) {
        float a = sVal[tid], c = sVal[tid + st];
        int ia = sIdx[tid], ic = sIdx[tid + st];
        if (c > a || (c == a && ic < ia)) { sVal[tid] = c; sIdx[tid] = ic; }
      }
      __syncthreads();
    }
    int nw = sIdx[0];
    __syncthreads();
    if (tid == 0) idx_out[b * KSEL + it] = nw;
    if (tid == nw) sel[tid] = 1;
    mind = fminf(mind, db[(size_t)tid * NN + nw] * invmaxd + sn);
    __syncthreads();
  }
}

// one block per batch: gather K rows, mean, LN -> out
__global__ __launch_bounds__(256) void pool_ln_kernel(const float* __restrict__ x,
                                                      const int* __restrict__ idx,
                                                      const float* __restrict__ gamma,
                                                      const float* __restrict__ beta,
                                                      float* __restrict__ out) {
  __shared__ float stmp[4];
  __shared__ int sIdx[KSEL];
  const int b = blockIdx.x;
  const int d = threadIdx.x;
  if (d < KSEL) sIdx[d] = idx[b * KSEL + d];
  __syncthreads();
  float acc = 0.f;
  #pragma unroll 4
  for (int kk = 0; kk < KSEL; ++kk)
    acc += x[((size_t)b * NN + sIdx[kk]) * DD + d];
  float p = acc * (1.0f / KSEL);
  float mu = blk_sum_256(p, stmp) * (1.0f / DD);
  float diff = p - mu;
  float var = blk_sum_256(diff * diff, stmp) * (1.0f / DD);
  out[b * DD + d] = diff * rsqrtf(var + 1e-6f) * gamma[d] + beta[d];
}

// ---------------- launcher ----------------
extern "C" void kernel_launch(void* const* d_in, const int* in_sizes, int n_in,
                              void* d_out, int out_size, void* d_ws, size_t ws_size,
                              hipStream_t stream) {
  (void)in_sizes; (void)n_in; (void)out_size; (void)ws_size;
  const float* x_in  = (const float*)d_in[0];
  const float* dist  = (const float*)d_in[1];
  const float* Wq    = (const float*)d_in[3];
  const float* Wk    = (const float*)d_in[4];
  const float* Wv    = (const float*)d_in[5];
  const float* Wo    = (const float*)d_in[6];
  const float* W1    = (const float*)d_in[7];
  const float* W2    = (const float*)d_in[8];
  const float* ln1_g = (const float*)d_in[9];
  const float* ln1_b = (const float*)d_in[10];
  const float* ln2_g = (const float*)d_in[11];
  const float* ln2_b = (const float*)d_in[12];
  const float* gamma = (const float*)d_in[13];
  const float* beta  = (const float*)d_in[14];

  float* ws   = (float*)d_ws;
  float* x    = ws + X_OFF;
  float* h    = ws + H_OFF;
  float* qb   = ws + Q_OFF;
  float* kb   = ws + K_OFF;
  float* vb   = ws + V_OFF;
  float* attn = ws + ATTN_OFF;
  float* ffn  = ws + FFN_OFF;
  float* sbuf = ws + S_OFF;
  int*   idxb = (int*)(ws + IDX_OFF);
  float* out  = (float*)d_out;

  copy_kernel<<<2048, 256, 0, stream>>>((const float4*)x_in, (float4*)x, 524288);
  hipMemsetAsync(sbuf, 0, BB * NN * sizeof(float), stream);

  const int M = BB * NN;  // 8192
  dim3 g1(DD / 64, M / 64);    // (4,128)
  dim3 g2(DFF / 64, M / 64);   // (16,128)
  dim3 ga(NN / 16, BB);        // (32,16)

  for (int l = 0; l < LL; ++l) {
    ln_kernel<<<M, 256, 0, stream>>>(x, ln1_g + l * DD, ln1_b + l * DD, h);
    gemm_kernel<0><<<g1, 256, 0, stream>>>(h, Wq + (size_t)l * DD * DD, nullptr, qb, M, DD, DD);
    gemm_kernel<0><<<g1, 256, 0, stream>>>(h, Wk + (size_t)l * DD * DD, nullptr, kb, M, DD, DD);
    gemm_kernel<0><<<g1, 256, 0, stream>>>(h, Wv + (size_t)l * DD * DD, nullptr, vb, M, DD, DD);
    attn_kernel<<<ga, 256, 0, stream>>>(qb, kb, vb, dist, attn, sbuf, (l == LL - 1) ? 1 : 0);
    gemm_kernel<1><<<g1, 256, 0, stream>>>(attn, Wo + (size_t)l * DD * DD, x, x, M, DD, DD);
    ln_kernel<<<M, 256, 0, stream>>>(x, ln2_g + l * DD, ln2_b + l * DD, h);
    gemm_kernel<2><<<g2, 256, 0, stream>>>(h, W1 + (size_t)l * DD * DFF, nullptr, ffn, M, DFF, DD);
    gemm_kernel<1><<<g1, 256, 0, stream>>>(ffn, W2 + (size_t)l * DD * DFF, x, x, M, DD, DFF);
  }
  afps_kernel<<<BB, 512, 0, stream>>>(dist, sbuf, idxb);
  pool_ln_kernel<<<BB, 256, 0, stream>>>(x, idxb, gamma, beta, out);
}

// Round 5
// 1531.623 us; speedup vs baseline: 2.9150x; 1.5835x over previous
//
#include <hip/hip_runtime.h>
#include <hip/hip_bf16.h>
#include <math.h>

// Problem: B=16, N=512, D=256, H=8, L=4, DFF=1024, K=128, DH=32
#define BB 16
#define NN 512
#define DD 256
#define HH 8
#define LL 4
#define DFF 1024
#define KSEL 128
#define DH 32

typedef __attribute__((ext_vector_type(8))) short bf16x8v;
typedef __attribute__((ext_vector_type(4))) float f32x4v;

// ---------------- workspace layout (byte offsets) ----------------
// x (fp32 8MB) | qkv fp32 24MB (ffn bf16 16MB overlays) | h bf16 4MB |
// attn bf16 4MB | WqkvT 1.5MB | WoT 0.5MB | W1T 2MB | W2T 2MB | s | idx
static const size_t X_B    = 0;
static const size_t QKV_B  = 8388608;
static const size_t H_B    = 33554432;
static const size_t ATT_B  = 37748736;
static const size_t WQKV_B = 41943040;
static const size_t WO_B   = 43515904;
static const size_t W1T_B  = 44040192;
static const size_t W2T_B  = 46137344;
static const size_t S_B    = 48234496;
static const size_t IDX_B  = 48267264;

// ---------------- helpers ----------------
__device__ __forceinline__ float gelu_f(float x) {
  float x3 = x * x * x;
  return 0.5f * x * (1.f + tanhf(0.7978845608028654f * (x + 0.044715f * x3)));
}

__device__ __forceinline__ float blk_sum_256(float v, float* stmp) {
  #pragma unroll
  for (int o = 32; o > 0; o >>= 1) v += __shfl_down(v, o, 64);
  if ((threadIdx.x & 63) == 0) stmp[threadIdx.x >> 6] = v;
  __syncthreads();
  if (threadIdx.x == 0) stmp[0] = stmp[0] + stmp[1] + stmp[2] + stmp[3];
  __syncthreads();
  float r = stmp[0];
  __syncthreads();
  return r;
}

// ---------------- kernels ----------------
__global__ void copy_kernel(const float4* __restrict__ src, float4* __restrict__ dst, int n) {
  int i = blockIdx.x * blockDim.x + threadIdx.x;
  if (i < n) dst[i] = src[i];
}

// one-shot: transpose-cast all weights to bf16.
// qkvT [L][768][256] (rows: 0-255 Wq cols, 256-511 Wk, 512-767 Wv)
// WoT [L][256][256], W1T [L][1024][256], W2T [L][256][1024]
__global__ __launch_bounds__(256) void cast_weights_kernel(
    const float* __restrict__ Wq, const float* __restrict__ Wk,
    const float* __restrict__ Wv, const float* __restrict__ Wo,
    const float* __restrict__ W1, const float* __restrict__ W2,
    __hip_bfloat16* __restrict__ qkvT, __hip_bfloat16* __restrict__ WoT,
    __hip_bfloat16* __restrict__ W1T, __hip_bfloat16* __restrict__ W2T) {
  int i = blockIdx.x * 256 + threadIdx.x;
  if (i < 786432) {                       // qkvT
    int l = i / 196608, r = i % 196608;
    int n = r >> 8, k = r & 255;
    const float* src = (n < 256) ? Wq : (n < 512 ? Wk : Wv);
    qkvT[i] = __float2bfloat16(src[l * 65536 + k * 256 + (n & 255)]);
  } else if (i < 1048576) {               // WoT
    int j = i - 786432;
    int l = j >> 16, r = j & 65535;
    int n = r >> 8, k = r & 255;
    WoT[j] = __float2bfloat16(Wo[l * 65536 + k * 256 + n]);
  } else if (i < 2097152) {               // W1T [n<1024][k<256]
    int j = i - 1048576;
    int l = j >> 18, r = j & 262143;
    int n = r >> 8, k = r & 255;
    W1T[j] = __float2bfloat16(W1[l * 262144 + k * 1024 + n]);
  } else {                                // W2T [n<256][k<1024]
    int j = i - 2097152;
    int l = j >> 18, r = j & 262143;
    int n = r >> 10, k = r & 1023;
    W2T[j] = __float2bfloat16(W2[l * 262144 + k * 256 + n]);
  }
}

// LayerNorm, writes bf16
__global__ __launch_bounds__(256) void ln_cast_kernel(const float* __restrict__ in,
                                                      const float* __restrict__ g,
                                                      const float* __restrict__ bb,
                                                      __hip_bfloat16* __restrict__ out) {
  __shared__ float stmp[4];
  size_t row = blockIdx.x;
  int d = threadIdx.x;
  float v = in[row * DD + d];
  float mu = blk_sum_256(v, stmp) * (1.0f / DD);
  float diff = v - mu;
  float var = blk_sum_256(diff * diff, stmp) * (1.0f / DD);
  out[row * DD + d] = __float2bfloat16(diff * rsqrtf(var + 1e-6f) * g[d] + bb[d]);
}

// MFMA bf16 GEMM: C[M,N] = op(A[M,K] @ Bt[N,K]^T)
// MODE 0: fp32 out; MODE 1: fp32 out = acc + Res; MODE 2: bf16 out = gelu(acc)
// block 256 (4 waves), 64x64 tile, BK=32. LDS rows padded to 40 halves (80B).
template <int MODE>
__global__ __launch_bounds__(256) void mfma_gemm(const __hip_bfloat16* __restrict__ A,
                                                 const __hip_bfloat16* __restrict__ Bt,
                                                 const float* __restrict__ Res,
                                                 void* __restrict__ Cv,
                                                 int M, int N, int Kd) {
  __shared__ short As[64 * 40];
  __shared__ short Bs[64 * 40];
  const int tid = threadIdx.x;
  const int w = tid >> 6, lane = tid & 63;
  const int m16 = lane & 15, quad = lane >> 4;
  const int bm = blockIdx.y << 6, bn = blockIdx.x << 6;
  const int srow = tid >> 2, scol = (tid & 3) << 3;

  f32x4v zero = {0.f, 0.f, 0.f, 0.f};
  f32x4v acc[4];
  #pragma unroll
  for (int nt = 0; nt < 4; ++nt) acc[nt] = zero;

  const short* Ag = (const short*)A;
  const short* Bg = (const short*)Bt;

  for (int k0 = 0; k0 < Kd; k0 += 32) {
    *(bf16x8v*)&As[srow * 40 + scol] =
        *(const bf16x8v*)(Ag + (size_t)(bm + srow) * Kd + k0 + scol);
    *(bf16x8v*)&Bs[srow * 40 + scol] =
        *(const bf16x8v*)(Bg + (size_t)(bn + srow) * Kd + k0 + scol);
    __syncthreads();
    bf16x8v af = *(bf16x8v*)&As[(w * 16 + m16) * 40 + (quad << 3)];
    #pragma unroll
    for (int nt = 0; nt < 4; ++nt) {
      bf16x8v bf = *(bf16x8v*)&Bs[(nt * 16 + m16) * 40 + (quad << 3)];
      acc[nt] = __builtin_amdgcn_mfma_f32_16x16x32_bf16(af, bf, acc[nt], 0, 0, 0);
    }
    __syncthreads();
  }

  const int erow = bm + w * 16 + quad * 4;
  #pragma unroll
  for (int nt = 0; nt < 4; ++nt) {
    int col = bn + nt * 16 + m16;
    #pragma unroll
    for (int r = 0; r < 4; ++r) {
      float v = acc[nt][r];
      size_t off = (size_t)(erow + r) * N + col;
      if (MODE == 1) {
        ((float*)Cv)[off] = v + Res[off];
      } else if (MODE == 2) {
        ((__hip_bfloat16*)Cv)[off] = __float2bfloat16(gelu_f(v));
      } else {
        ((float*)Cv)[off] = v;
      }
    }
  }
}

// Flash-style attention. qkv fp32 [B*N][768] (q|k|v). out bf16 [B*N][256].
// block 256 = 16 q x 16 hh (h*2+half). grid (N/16, B). 16-key LDS tiles.
// LDS ~34 KB -> 4 blocks/CU.
__global__ __launch_bounds__(256) void attn_kernel(const float* __restrict__ qkv,
                                                   const float* __restrict__ dist,
                                                   __hip_bfloat16* __restrict__ outg,
                                                   float* __restrict__ s_acc,
                                                   int accum) {
  __shared__ float Ks[16 * 256];
  __shared__ float Vs[16 * 256];
  __shared__ float Ds[16][17];
  __shared__ float sPart[4][16];

  const int tid = threadIdx.x;
  const int q = tid & 15;
  const int hh = tid >> 4;     // 0..15
  const int doff = hh * 16;
  const int b = blockIdx.y;
  const int qbase = blockIdx.x * 16;
  const size_t rowq = (size_t)b * NN + qbase + q;
  const float scale = 0.17677669529663687f;

  float qreg[16];
  {
    const float* qp = qkv + rowq * 768 + doff;
    #pragma unroll
    for (int i = 0; i < 4; ++i) {
      float4 t = *(const float4*)(qp + i * 4);
      qreg[i * 4 + 0] = t.x; qreg[i * 4 + 1] = t.y;
      qreg[i * 4 + 2] = t.z; qreg[i * 4 + 3] = t.w;
    }
  }

  float O[16] = {};
  float l = 0.f;
  const float4* qkv4 = (const float4*)qkv;

  for (int t0 = 0; t0 < NN; t0 += 16) {
    #pragma unroll
    for (int rr = 0; rr < 4; ++rr) {
      int idx = rr * 256 + tid;         // 0..1023
      int row = idx >> 6, col = idx & 63;
      size_t base = ((size_t)b * NN + t0 + row) * 192;
      ((float4*)Ks)[idx] = qkv4[base + 64 + col];
      ((float4*)Vs)[idx] = qkv4[base + 128 + col];
    }
    if (tid < 64) {
      int qq = tid >> 2, c4 = tid & 3;
      float4 dv = *(const float4*)(dist + ((size_t)b * NN + qbase + qq) * NN + t0 + c4 * 4);
      Ds[qq][c4 * 4 + 0] = dv.x; Ds[qq][c4 * 4 + 1] = dv.y;
      Ds[qq][c4 * 4 + 2] = dv.z; Ds[qq][c4 * 4 + 3] = dv.w;
    }
    __syncthreads();
    #pragma unroll 4
    for (int j = 0; j < 16; ++j) {
      const float* kr = Ks + j * 256 + doff;
      float d0 = 0.f, d1 = 0.f;
      #pragma unroll
      for (int i = 0; i < 2; ++i) {
        float4 ka = ((const float4*)kr)[i * 2];
        float4 kb2 = ((const float4*)kr)[i * 2 + 1];
        d0 = fmaf(qreg[i * 8 + 0], ka.x, d0);
        d1 = fmaf(qreg[i * 8 + 1], ka.y, d1);
        d0 = fmaf(qreg[i * 8 + 2], ka.z, d0);
        d1 = fmaf(qreg[i * 8 + 3], ka.w, d1);
        d0 = fmaf(qreg[i * 8 + 4], kb2.x, d0);
        d1 = fmaf(qreg[i * 8 + 5], kb2.y, d1);
        d0 = fmaf(qreg[i * 8 + 6], kb2.z, d0);
        d1 = fmaf(qreg[i * 8 + 7], kb2.w, d1);
      }
      float ds = d0 + d1;
      float dot = ds + __shfl_xor(ds, 16, 64);
      float logit = fmaf(dot, scale, -Ds[q][j]);
      float e = __expf(logit);
      l += e;
      const float* vr = Vs + j * 256 + doff;
      #pragma unroll
      for (int i = 0; i < 4; ++i) {
        float4 vv = ((const float4*)vr)[i];
        O[i * 4 + 0] = fmaf(e, vv.x, O[i * 4 + 0]);
        O[i * 4 + 1] = fmaf(e, vv.y, O[i * 4 + 1]);
        O[i * 4 + 2] = fmaf(e, vv.z, O[i * 4 + 2]);
        O[i * 4 + 3] = fmaf(e, vv.w, O[i * 4 + 3]);
      }
    }
    __syncthreads();
  }

  float invl = 1.f / l;
  {
    __hip_bfloat16* op = outg + rowq * DD + doff;
    #pragma unroll
    for (int i = 0; i < 16; ++i) op[i] = __float2bfloat16(O[i] * invl);
  }

  // last layer: s[b,k] = sum_q mean_h p[q,k]  (recompute QK only)
  if (accum) {
    const int waveid = tid >> 6;
    for (int t0 = 0; t0 < NN; t0 += 16) {
      #pragma unroll
      for (int rr = 0; rr < 4; ++rr) {
        int idx = rr * 256 + tid;
        int row = idx >> 6, col = idx & 63;
        ((float4*)Ks)[idx] = qkv4[((size_t)b * NN + t0 + row) * 192 + 64 + col];
      }
      if (tid < 64) {
        int qq = tid >> 2, c4 = tid & 3;
        float4 dv = *(const float4*)(dist + ((size_t)b * NN + qbase + qq) * NN + t0 + c4 * 4);
        Ds[qq][c4 * 4 + 0] = dv.x; Ds[qq][c4 * 4 + 1] = dv.y;
        Ds[qq][c4 * 4 + 2] = dv.z; Ds[qq][c4 * 4 + 3] = dv.w;
      }
      __syncthreads();
      #pragma unroll 2
      for (int j = 0; j < 16; ++j) {
        const float* kr = Ks + j * 256 + doff;
        float d0 = 0.f, d1 = 0.f;
        #pragma unroll
        for (int i = 0; i < 2; ++i) {
          float4 ka = ((const float4*)kr)[i * 2];
          float4 kb2 = ((const float4*)kr)[i * 2 + 1];
          d0 = fmaf(qreg[i * 8 + 0], ka.x, d0);
          d1 = fmaf(qreg[i * 8 + 1], ka.y, d1);
          d0 = fmaf(qreg[i * 8 + 2], ka.z, d0);
          d1 = fmaf(qreg[i * 8 + 3], ka.w, d1);
          d0 = fmaf(qreg[i * 8 + 4], kb2.x, d0);
          d1 = fmaf(qreg[i * 8 + 5], kb2.y, d1);
          d0 = fmaf(qreg[i * 8 + 6], kb2.z, d0);
          d1 = fmaf(qreg[i * 8 + 7], kb2.w, d1);
        }
        float ds = d0 + d1;
        float dot = ds + __shfl_xor(ds, 16, 64);
        float p = __expf(fmaf(dot, scale, -Ds[q][j])) * invl;
        #pragma unroll
        for (int o = 32; o > 0; o >>= 1) p += __shfl_xor(p, o, 64);
        if ((tid & 63) == 0) sPart[waveid][j] = p;
      }
      __syncthreads();
      if (tid < 16) {
        float sv = (sPart[0][tid] + sPart[1][tid] + sPart[2][tid] + sPart[3][tid]) * (1.0f / 16.0f);
        atomicAdd(&s_acc[b * NN + t0 + tid], sv);
      }
      __syncthreads();
    }
  }
}

// one block per batch: sequential farthest-point sampling (matches jax ref)
__global__ __launch_bounds__(512) void afps_kernel(const float* __restrict__ dist,
                                                   const float* __restrict__ s,
                                                   int* __restrict__ idx_out) {
  __shared__ float sVal[512];
  __shared__ int sIdx[512];
  __shared__ int sel[512];
  const int b = blockIdx.x;
  const int tid = threadIdx.x;
  const float* db = dist + (size_t)b * NN * NN;
  float m = 0.f;
  for (int i = tid; i < NN * NN; i += 512) m = fmaxf(m, db[i]);
  sVal[tid] = m;
  __syncthreads();
  for (int st = 256; st > 0; st >>= 1) {
    if (tid < st) sVal[tid] = fmaxf(sVal[tid], sVal[tid + st]);
    __syncthreads();
  }
  float maxd = sVal[0];
  __syncthreads();
  sVal[tid] = s[b * NN + tid];
  __syncthreads();
  for (int st = 256; st > 0; st >>= 1) {
    if (tid < st) sVal[tid] = fmaxf(sVal[tid], sVal[tid + st]);
    __syncthreads();
  }
  float maxs = sVal[0];
  __syncthreads();

  float invmaxd = 1.0f / maxd;
  float sn = (s[b * NN + tid] / maxs) * 0.1f;
  float mind = db[(size_t)tid * NN + 0] * invmaxd + sn;
  sel[tid] = (tid == 0) ? 1 : 0;
  if (tid == 0) idx_out[b * KSEL + 0] = 0;
  __syncthreads();
  for (int it = 1; it < KSEL; ++it) {
    sVal[tid] = sel[tid] ? -INFINITY : mind;
    sIdx[tid] = tid;
    __syncthreads();
    for (int st = 256; st > 0; st >>= 1) {
      if (tid < st) {
        float a = sVal[tid], c = sVal[tid + st];
        int ia = sIdx[tid], ic = sIdx[tid + st];
        if (c > a || (c == a && ic < ia)) { sVal[tid] = c; sIdx[tid] = ic; }
      }
      __syncthreads();
    }
    int nw = sIdx[0];
    __syncthreads();
    if (tid == 0) idx_out[b * KSEL + it] = nw;
    if (tid == nw) sel[tid] = 1;
    mind = fminf(mind, db[(size_t)tid * NN + nw] * invmaxd + sn);
    __syncthreads();
  }
}

// one block per batch: gather K rows, mean, LN -> out
__global__ __launch_bounds__(256) void pool_ln_kernel(const float* __restrict__ x,
                                                      const int* __restrict__ idx,
                                                      const float* __restrict__ gamma,
                                                      const float* __restrict__ beta,
                                                      float* __restrict__ out) {
  __shared__ float stmp[4];
  __shared__ int sIdx[KSEL];
  const int b = blockIdx.x;
  const int d = threadIdx.x;
  if (d < KSEL) sIdx[d] = idx[b * KSEL + d];
  __syncthreads();
  float acc = 0.f;
  #pragma unroll 4
  for (int kk = 0; kk < KSEL; ++kk)
    acc += x[((size_t)b * NN + sIdx[kk]) * DD + d];
  float p = acc * (1.0f / KSEL);
  float mu = blk_sum_256(p, stmp) * (1.0f / DD);
  float diff = p - mu;
  float var = blk_sum_256(diff * diff, stmp) * (1.0f / DD);
  out[b * DD + d] = diff * rsqrtf(var + 1e-6f) * gamma[d] + beta[d];
}

// ---------------- launcher ----------------
extern "C" void kernel_launch(void* const* d_in, const int* in_sizes, int n_in,
                              void* d_out, int out_size, void* d_ws, size_t ws_size,
                              hipStream_t stream) {
  (void)in_sizes; (void)n_in; (void)out_size; (void)ws_size;
  const float* x_in  = (const float*)d_in[0];
  const float* dist  = (const float*)d_in[1];
  const float* Wq    = (const float*)d_in[3];
  const float* Wk    = (const float*)d_in[4];
  const float* Wv    = (const float*)d_in[5];
  const float* Wo    = (const float*)d_in[6];
  const float* W1    = (const float*)d_in[7];
  const float* W2    = (const float*)d_in[8];
  const float* ln1_g = (const float*)d_in[9];
  const float* ln1_b = (const float*)d_in[10];
  const float* ln2_g = (const float*)d_in[11];
  const float* ln2_b = (const float*)d_in[12];
  const float* gamma = (const float*)d_in[13];
  const float* beta  = (const float*)d_in[14];

  char* wsb = (char*)d_ws;
  float* x            = (float*)(wsb + X_B);
  float* qkv          = (float*)(wsb + QKV_B);
  __hip_bfloat16* ffn = (__hip_bfloat16*)(wsb + QKV_B);   // overlays qkv
  __hip_bfloat16* hb  = (__hip_bfloat16*)(wsb + H_B);
  __hip_bfloat16* ab  = (__hip_bfloat16*)(wsb + ATT_B);
  __hip_bfloat16* WqkvT = (__hip_bfloat16*)(wsb + WQKV_B);
  __hip_bfloat16* WoT   = (__hip_bfloat16*)(wsb + WO_B);
  __hip_bfloat16* W1T   = (__hip_bfloat16*)(wsb + W1T_B);
  __hip_bfloat16* W2T   = (__hip_bfloat16*)(wsb + W2T_B);
  float* sbuf = (float*)(wsb + S_B);
  int*   idxb = (int*)(wsb + IDX_B);
  float* out  = (float*)d_out;

  copy_kernel<<<2048, 256, 0, stream>>>((const float4*)x_in, (float4*)x, 524288);
  hipMemsetAsync(sbuf, 0, BB * NN * sizeof(float), stream);
  cast_weights_kernel<<<12288, 256, 0, stream>>>(Wq, Wk, Wv, Wo, W1, W2,
                                                 WqkvT, WoT, W1T, W2T);

  const int M = BB * NN;  // 8192
  dim3 gqkv(768 / 64, M / 64);   // (12,128)
  dim3 go(DD / 64, M / 64);      // (4,128)
  dim3 gf(DFF / 64, M / 64);     // (16,128)
  dim3 ga(NN / 16, BB);          // (32,16)

  for (int l = 0; l < LL; ++l) {
    ln_cast_kernel<<<M, 256, 0, stream>>>(x, ln1_g + l * DD, ln1_b + l * DD, hb);
    mfma_gemm<0><<<gqkv, 256, 0, stream>>>(hb, WqkvT + (size_t)l * 768 * 256, nullptr,
                                           qkv, M, 768, 256);
    attn_kernel<<<ga, 256, 0, stream>>>(qkv, dist, ab, sbuf, (l == LL - 1) ? 1 : 0);
    mfma_gemm<1><<<go, 256, 0, stream>>>(ab, WoT + (size_t)l * 65536, x, x, M, DD, 256);
    ln_cast_kernel<<<M, 256, 0, stream>>>(x, ln2_g + l * DD, ln2_b + l * DD, hb);
    mfma_gemm<2><<<gf, 256, 0, stream>>>(hb, W1T + (size_t)l * 262144, nullptr,
                                         ffn, M, DFF, 256);
    mfma_gemm<1><<<go, 256, 0, stream>>>(ffn, W2T + (size_t)l * 262144, x, x, M, DD, 1024);
  }
  afps_kernel<<<BB, 512, 0, stream>>>(dist, sbuf, idxb);
  pool_ln_kernel<<<BB, 256, 0, stream>>>(x, idxb, gamma, beta, out);
}

// Round 6
// 873.860 us; speedup vs baseline: 5.1091x; 1.7527x over previous
//
#include <hip/hip_runtime.h>
#include <hip/hip_bf16.h>
#include <math.h>

// Problem: B=16, N=512, D=256, H=8, L=4, DFF=1024, K=128, DH=32
#define BB 16
#define NN 512
#define DD 256
#define HH 8
#define LL 4
#define DFF 1024
#define KSEL 128
#define DH 32

typedef __attribute__((ext_vector_type(8))) short bf16x8v;
typedef __attribute__((ext_vector_type(4))) float f32x4v;

// ---------------- workspace layout (byte offsets) ----------------
// x fp32 8MB | qkvb bf16 [8192][768] 12MB | Vt bf16 [16][256][512] 4MB
// (ffn bf16 16MB overlays qkvb+Vt) | hb 4MB | ab 4MB | weights | s | idx
static const size_t X_B    = 0;
static const size_t QKVB_B = 8388608;
static const size_t VT_B   = 20971520;
static const size_t FFN_B  = 8388608;    // overlays qkvb+Vt (dead during FFN)
static const size_t H_B    = 25165824;
static const size_t ATT_B  = 29360128;
static const size_t WQKV_B = 33554432;
static const size_t WO_B   = 35127296;
static const size_t W1T_B  = 35651584;
static const size_t W2T_B  = 37748736;
static const size_t S_B    = 39845888;
static const size_t IDX_B  = 39878656;

// ---------------- helpers ----------------
__device__ __forceinline__ float gelu_f(float x) {
  float x3 = x * x * x;
  return 0.5f * x * (1.f + tanhf(0.7978845608028654f * (x + 0.044715f * x3)));
}

__device__ __forceinline__ short bf16raw(float v) {
  __hip_bfloat16 h = __float2bfloat16(v);
  return *reinterpret_cast<short*>(&h);
}

__device__ __forceinline__ float blk_sum_256(float v, float* stmp) {
  #pragma unroll
  for (int o = 32; o > 0; o >>= 1) v += __shfl_down(v, o, 64);
  if ((threadIdx.x & 63) == 0) stmp[threadIdx.x >> 6] = v;
  __syncthreads();
  if (threadIdx.x == 0) stmp[0] = stmp[0] + stmp[1] + stmp[2] + stmp[3];
  __syncthreads();
  float r = stmp[0];
  __syncthreads();
  return r;
}

// ---------------- kernels ----------------
__global__ void copy_kernel(const float4* __restrict__ src, float4* __restrict__ dst, int n) {
  int i = blockIdx.x * blockDim.x + threadIdx.x;
  if (i < n) dst[i] = src[i];
}

// one-shot: transpose-cast all weights to bf16.
__global__ __launch_bounds__(256) void cast_weights_kernel(
    const float* __restrict__ Wq, const float* __restrict__ Wk,
    const float* __restrict__ Wv, const float* __restrict__ Wo,
    const float* __restrict__ W1, const float* __restrict__ W2,
    __hip_bfloat16* __restrict__ qkvT, __hip_bfloat16* __restrict__ WoT,
    __hip_bfloat16* __restrict__ W1T, __hip_bfloat16* __restrict__ W2T) {
  int i = blockIdx.x * 256 + threadIdx.x;
  if (i < 786432) {                       // qkvT [L][768 n][256 k]
    int l = i / 196608, r = i % 196608;
    int n = r >> 8, k = r & 255;
    const float* src = (n < 256) ? Wq : (n < 512 ? Wk : Wv);
    qkvT[i] = __float2bfloat16(src[l * 65536 + k * 256 + (n & 255)]);
  } else if (i < 1048576) {               // WoT [L][256][256]
    int j = i - 786432;
    int l = j >> 16, r = j & 65535;
    int n = r >> 8, k = r & 255;
    WoT[j] = __float2bfloat16(Wo[l * 65536 + k * 256 + n]);
  } else if (i < 2097152) {               // W1T [L][1024 n][256 k]
    int j = i - 1048576;
    int l = j >> 18, r = j & 262143;
    int n = r >> 8, k = r & 255;
    W1T[j] = __float2bfloat16(W1[l * 262144 + k * 1024 + n]);
  } else {                                // W2T [L][256 n][1024 k]
    int j = i - 2097152;
    int l = j >> 18, r = j & 262143;
    int n = r >> 10, k = r & 1023;
    W2T[j] = __float2bfloat16(W2[l * 262144 + k * 256 + n]);
  }
}

// LayerNorm, writes bf16
__global__ __launch_bounds__(256) void ln_cast_kernel(const float* __restrict__ in,
                                                      const float* __restrict__ g,
                                                      const float* __restrict__ bb,
                                                      __hip_bfloat16* __restrict__ out) {
  __shared__ float stmp[4];
  size_t row = blockIdx.x;
  int d = threadIdx.x;
  float v = in[row * DD + d];
  float mu = blk_sum_256(v, stmp) * (1.0f / DD);
  float diff = v - mu;
  float var = blk_sum_256(diff * diff, stmp) * (1.0f / DD);
  out[row * DD + d] = __float2bfloat16(diff * rsqrtf(var + 1e-6f) * g[d] + bb[d]);
}

// MFMA bf16 GEMM: acc = A[M,K] @ Bt[N,K]^T
// MODE 1: fp32 out = acc + Res; MODE 2: bf16 out = gelu(acc);
// MODE 3: qkv: cols<512 -> bf16 qkvb row-major (pitch 768);
//              cols>=512 -> Vt[b][dim][key] transposed bf16.
template <int MODE>
__global__ __launch_bounds__(256) void mfma_gemm(const __hip_bfloat16* __restrict__ A,
                                                 const __hip_bfloat16* __restrict__ Bt,
                                                 const float* __restrict__ Res,
                                                 void* __restrict__ Cv,
                                                 __hip_bfloat16* __restrict__ Vto,
                                                 int M, int N, int Kd) {
  __shared__ short As[64 * 40];
  __shared__ short Bs[64 * 40];
  const int tid = threadIdx.x;
  const int w = tid >> 6, lane = tid & 63;
  const int m16 = lane & 15, quad = lane >> 4;
  const int bm = blockIdx.y << 6, bn = blockIdx.x << 6;
  const int srow = tid >> 2, scol = (tid & 3) << 3;

  f32x4v zero = {0.f, 0.f, 0.f, 0.f};
  f32x4v acc[4];
  #pragma unroll
  for (int nt = 0; nt < 4; ++nt) acc[nt] = zero;

  const short* Ag = (const short*)A;
  const short* Bg = (const short*)Bt;

  for (int k0 = 0; k0 < Kd; k0 += 32) {
    *(bf16x8v*)&As[srow * 40 + scol] =
        *(const bf16x8v*)(Ag + (size_t)(bm + srow) * Kd + k0 + scol);
    *(bf16x8v*)&Bs[srow * 40 + scol] =
        *(const bf16x8v*)(Bg + (size_t)(bn + srow) * Kd + k0 + scol);
    __syncthreads();
    bf16x8v af = *(bf16x8v*)&As[(w * 16 + m16) * 40 + (quad << 3)];
    #pragma unroll
    for (int nt = 0; nt < 4; ++nt) {
      bf16x8v bf = *(bf16x8v*)&Bs[(nt * 16 + m16) * 40 + (quad << 3)];
      acc[nt] = __builtin_amdgcn_mfma_f32_16x16x32_bf16(af, bf, acc[nt], 0, 0, 0);
    }
    __syncthreads();
  }

  const int erow = bm + w * 16 + quad * 4;
  #pragma unroll
  for (int nt = 0; nt < 4; ++nt) {
    int col = bn + nt * 16 + m16;
    if (MODE == 3) {
      if (col < 512) {
        #pragma unroll
        for (int r = 0; r < 4; ++r)
          ((__hip_bfloat16*)Cv)[(size_t)(erow + r) * 768 + col] =
              __float2bfloat16(acc[nt][r]);
      } else {
        short4 pk;
        pk.x = bf16raw(acc[nt][0]); pk.y = bf16raw(acc[nt][1]);
        pk.z = bf16raw(acc[nt][2]); pk.w = bf16raw(acc[nt][3]);
        int bb2 = erow >> 9, key = erow & 511, dim = col - 512;
        *(short4*)((short*)Vto + (size_t)bb2 * 131072 + (size_t)dim * 512 + key) = pk;
      }
    } else {
      #pragma unroll
      for (int r = 0; r < 4; ++r) {
        float v = acc[nt][r];
        size_t off = (size_t)(erow + r) * N + col;
        if (MODE == 1) ((float*)Cv)[off] = v + Res[off];
        else ((__hip_bfloat16*)Cv)[off] = __float2bfloat16(gelu_f(v));
      }
    }
  }
}

// MFMA flash attention, barrier-free.
// block 512 = 8 waves (wave = head). grid (N/16 q-tiles, B).
// Q/K from qkvb bf16 [row][768]; V^T from vt bf16 [b][256 dim][512 key].
// S = 2x mfma_16x16x32 (K=32=DH); softmax in C-layout regs; P via
// wave-private LDS (pitch 36 f32) -> A-frag; PV = 2x mfma into O.
__global__ __launch_bounds__(512) void attn_kernel(const __hip_bfloat16* __restrict__ qkvb,
                                                   const __hip_bfloat16* __restrict__ vt,
                                                   const float* __restrict__ dist,
                                                   __hip_bfloat16* __restrict__ outg,
                                                   float* __restrict__ s_acc,
                                                   int accum) {
  __shared__ float Pf[8][16 * 36];
  const int tid = threadIdx.x;
  const int h = tid >> 6, lane = tid & 63;
  const int m16 = lane & 15, quad = lane >> 4;
  const int b = blockIdx.y;
  const int qbase = blockIdx.x * 16;
  const float scale = 0.17677669529663687f;
  const f32x4v zero = {0.f, 0.f, 0.f, 0.f};

  const short* qkvs = (const short*)qkvb;
  const short* vts = (const short*)vt + (size_t)b * 131072;
  float* Pw = Pf[h];

  bf16x8v qf = *(const bf16x8v*)(qkvs + ((size_t)(b * NN + qbase + m16)) * 768 + h * 32 + (quad << 3));

  int drow[4];
  #pragma unroll
  for (int r = 0; r < 4; ++r) drow[r] = (b * NN + qbase + quad * 4 + r) * NN;

  f32x4v accO0 = zero, accO1 = zero;
  float lacc[4] = {0.f, 0.f, 0.f, 0.f};

  for (int t0 = 0; t0 < NN; t0 += 32) {
    bf16x8v kf0 = *(const bf16x8v*)(qkvs + ((size_t)(b * NN + t0 + m16)) * 768 + 256 + h * 32 + (quad << 3));
    bf16x8v kf1 = *(const bf16x8v*)(qkvs + ((size_t)(b * NN + t0 + 16 + m16)) * 768 + 256 + h * 32 + (quad << 3));
    f32x4v s0 = __builtin_amdgcn_mfma_f32_16x16x32_bf16(qf, kf0, zero, 0, 0, 0);
    f32x4v s1 = __builtin_amdgcn_mfma_f32_16x16x32_bf16(qf, kf1, zero, 0, 0, 0);
    #pragma unroll
    for (int r = 0; r < 4; ++r) {
      float e0 = __expf(fmaf(s0[r], scale, -dist[drow[r] + t0 + m16]));
      float e1 = __expf(fmaf(s1[r], scale, -dist[drow[r] + t0 + 16 + m16]));
      float t = e0 + e1;
      t += __shfl_xor(t, 1, 64); t += __shfl_xor(t, 2, 64);
      t += __shfl_xor(t, 4, 64); t += __shfl_xor(t, 8, 64);
      lacc[r] += t;
      Pw[(quad * 4 + r) * 36 + m16] = e0;
      Pw[(quad * 4 + r) * 36 + 16 + m16] = e1;
    }
    // P A-frag: lane q=m16 reads keys quad*8..quad*8+7 (aligned b128 reads)
    bf16x8v pfr;
    {
      const float* pr = &Pw[m16 * 36 + (quad << 3)];
      float4 pa = *(const float4*)pr;
      float4 pb = *(const float4*)(pr + 4);
      pfr[0] = bf16raw(pa.x); pfr[1] = bf16raw(pa.y);
      pfr[2] = bf16raw(pa.z); pfr[3] = bf16raw(pa.w);
      pfr[4] = bf16raw(pb.x); pfr[5] = bf16raw(pb.y);
      pfr[6] = bf16raw(pb.z); pfr[7] = bf16raw(pb.w);
    }
    bf16x8v vf0 = *(const bf16x8v*)(vts + (size_t)(h * 32 + m16) * 512 + t0 + (quad << 3));
    bf16x8v vf1 = *(const bf16x8v*)(vts + (size_t)(h * 32 + 16 + m16) * 512 + t0 + (quad << 3));
    accO0 = __builtin_amdgcn_mfma_f32_16x16x32_bf16(pfr, vf0, accO0, 0, 0, 0);
    accO1 = __builtin_amdgcn_mfma_f32_16x16x32_bf16(pfr, vf1, accO1, 0, 0, 0);
  }

  float invl[4];
  #pragma unroll
  for (int r = 0; r < 4; ++r) invl[r] = 1.f / lacc[r];

  #pragma unroll
  for (int r = 0; r < 4; ++r) {
    size_t orow = (size_t)(b * NN + qbase + quad * 4 + r) * DD + h * 32;
    outg[orow + m16] = __float2bfloat16(accO0[r] * invl[r]);
    outg[orow + 16 + m16] = __float2bfloat16(accO1[r] * invl[r]);
  }

  // last layer: s[b,k] = sum_q mean_h p[q,k]  (S-only second pass)
  if (accum) {
    for (int t0 = 0; t0 < NN; t0 += 32) {
      bf16x8v kf0 = *(const bf16x8v*)(qkvs + ((size_t)(b * NN + t0 + m16)) * 768 + 256 + h * 32 + (quad << 3));
      bf16x8v kf1 = *(const bf16x8v*)(qkvs + ((size_t)(b * NN + t0 + 16 + m16)) * 768 + 256 + h * 32 + (quad << 3));
      f32x4v s0 = __builtin_amdgcn_mfma_f32_16x16x32_bf16(qf, kf0, zero, 0, 0, 0);
      f32x4v s1 = __builtin_amdgcn_mfma_f32_16x16x32_bf16(qf, kf1, zero, 0, 0, 0);
      float p0 = 0.f, p1 = 0.f;
      #pragma unroll
      for (int r = 0; r < 4; ++r) {
        p0 += __expf(fmaf(s0[r], scale, -dist[drow[r] + t0 + m16])) * invl[r];
        p1 += __expf(fmaf(s1[r], scale, -dist[drow[r] + t0 + 16 + m16])) * invl[r];
      }
      p0 += __shfl_xor(p0, 16, 64); p0 += __shfl_xor(p0, 32, 64);
      p1 += __shfl_xor(p1, 16, 64); p1 += __shfl_xor(p1, 32, 64);
      if (quad == 0) {
        atomicAdd(&s_acc[b * NN + t0 + m16], p0 * 0.125f);
        atomicAdd(&s_acc[b * NN + t0 + 16 + m16], p1 * 0.125f);
      }
    }
  }
}

// one block per batch: sequential farthest-point sampling (matches jax ref)
__global__ __launch_bounds__(512) void afps_kernel(const float* __restrict__ dist,
                                                   const float* __restrict__ s,
                                                   int* __restrict__ idx_out) {
  __shared__ float sVal[512];
  __shared__ int sIdx[512];
  __shared__ int sel[512];
  const int b = blockIdx.x;
  const int tid = threadIdx.x;
  const float* db = dist + (size_t)b * NN * NN;
  float m = 0.f;
  for (int i = tid; i < NN * NN; i += 512) m = fmaxf(m, db[i]);
  sVal[tid] = m;
  __syncthreads();
  for (int st = 256; st > 0; st >>= 1) {
    if (tid < st) sVal[tid] = fmaxf(sVal[tid], sVal[tid + st]);
    __syncthreads();
  }
  float maxd = sVal[0];
  __syncthreads();
  sVal[tid] = s[b * NN + tid];
  __syncthreads();
  for (int st = 256; st > 0; st >>= 1) {
    if (tid < st) sVal[tid] = fmaxf(sVal[tid], sVal[tid + st]);
    __syncthreads();
  }
  float maxs = sVal[0];
  __syncthreads();

  float invmaxd = 1.0f / maxd;
  float sn = (s[b * NN + tid] / maxs) * 0.1f;
  float mind = db[(size_t)tid * NN + 0] * invmaxd + sn;
  sel[tid] = (tid == 0) ? 1 : 0;
  if (tid == 0) idx_out[b * KSEL + 0] = 0;
  __syncthreads();
  for (int it = 1; it < KSEL; ++it) {
    sVal[tid] = sel[tid] ? -INFINITY : mind;
    sIdx[tid] = tid;
    __syncthreads();
    for (int st = 256; st > 0; st >>= 1) {
      if (tid < st) {
        float a = sVal[tid], c = sVal[tid + st];
        int ia = sIdx[tid], ic = sIdx[tid + st];
        if (c > a || (c == a && ic < ia)) { sVal[tid] = c; sIdx[tid] = ic; }
      }
      __syncthreads();
    }
    int nw = sIdx[0];
    __syncthreads();
    if (tid == 0) idx_out[b * KSEL + it] = nw;
    if (tid == nw) sel[tid] = 1;
    mind = fminf(mind, db[(size_t)tid * NN + nw] * invmaxd + sn);
    __syncthreads();
  }
}

// one block per batch: gather K rows, mean, LN -> out
__global__ __launch_bounds__(256) void pool_ln_kernel(const float* __restrict__ x,
                                                      const int* __restrict__ idx,
                                                      const float* __restrict__ gamma,
                                                      const float* __restrict__ beta,
                                                      float* __restrict__ out) {
  __shared__ float stmp[4];
  __shared__ int sIdx[KSEL];
  const int b = blockIdx.x;
  const int d = threadIdx.x;
  if (d < KSEL) sIdx[d] = idx[b * KSEL + d];
  __syncthreads();
  float acc = 0.f;
  #pragma unroll 4
  for (int kk = 0; kk < KSEL; ++kk)
    acc += x[((size_t)b * NN + sIdx[kk]) * DD + d];
  float p = acc * (1.0f / KSEL);
  float mu = blk_sum_256(p, stmp) * (1.0f / DD);
  float diff = p - mu;
  float var = blk_sum_256(diff * diff, stmp) * (1.0f / DD);
  out[b * DD + d] = diff * rsqrtf(var + 1e-6f) * gamma[d] + beta[d];
}

// ---------------- launcher ----------------
extern "C" void kernel_launch(void* const* d_in, const int* in_sizes, int n_in,
                              void* d_out, int out_size, void* d_ws, size_t ws_size,
                              hipStream_t stream) {
  (void)in_sizes; (void)n_in; (void)out_size; (void)ws_size;
  const float* x_in  = (const float*)d_in[0];
  const float* dist  = (const float*)d_in[1];
  const float* Wq    = (const float*)d_in[3];
  const float* Wk    = (const float*)d_in[4];
  const float* Wv    = (const float*)d_in[5];
  const float* Wo    = (const float*)d_in[6];
  const float* W1    = (const float*)d_in[7];
  const float* W2    = (const float*)d_in[8];
  const float* ln1_g = (const float*)d_in[9];
  const float* ln1_b = (const float*)d_in[10];
  const float* ln2_g = (const float*)d_in[11];
  const float* ln2_b = (const float*)d_in[12];
  const float* gamma = (const float*)d_in[13];
  const float* beta  = (const float*)d_in[14];

  char* wsb = (char*)d_ws;
  float* x              = (float*)(wsb + X_B);
  __hip_bfloat16* qkvb  = (__hip_bfloat16*)(wsb + QKVB_B);
  __hip_bfloat16* vtb   = (__hip_bfloat16*)(wsb + VT_B);
  __hip_bfloat16* ffn   = (__hip_bfloat16*)(wsb + FFN_B);
  __hip_bfloat16* hb    = (__hip_bfloat16*)(wsb + H_B);
  __hip_bfloat16* ab    = (__hip_bfloat16*)(wsb + ATT_B);
  __hip_bfloat16* WqkvT = (__hip_bfloat16*)(wsb + WQKV_B);
  __hip_bfloat16* WoT   = (__hip_bfloat16*)(wsb + WO_B);
  __hip_bfloat16* W1T   = (__hip_bfloat16*)(wsb + W1T_B);
  __hip_bfloat16* W2T   = (__hip_bfloat16*)(wsb + W2T_B);
  float* sbuf = (float*)(wsb + S_B);
  int*   idxb = (int*)(wsb + IDX_B);
  float* out  = (float*)d_out;

  copy_kernel<<<2048, 256, 0, stream>>>((const float4*)x_in, (float4*)x, 524288);
  hipMemsetAsync(sbuf, 0, BB * NN * sizeof(float), stream);
  cast_weights_kernel<<<12288, 256, 0, stream>>>(Wq, Wk, Wv, Wo, W1, W2,
                                                 WqkvT, WoT, W1T, W2T);

  const int M = BB * NN;  // 8192
  dim3 gqkv(768 / 64, M / 64);   // (12,128)
  dim3 go(DD / 64, M / 64);      // (4,128)
  dim3 gf(DFF / 64, M / 64);     // (16,128)
  dim3 ga(NN / 16, BB);          // (32,16)

  for (int l = 0; l < LL; ++l) {
    ln_cast_kernel<<<M, 256, 0, stream>>>(x, ln1_g + l * DD, ln1_b + l * DD, hb);
    mfma_gemm<3><<<gqkv, 256, 0, stream>>>(hb, WqkvT + (size_t)l * 768 * 256, nullptr,
                                           qkvb, vtb, M, 768, 256);
    attn_kernel<<<ga, 512, 0, stream>>>(qkvb, vtb, dist, ab, sbuf, (l == LL - 1) ? 1 : 0);
    mfma_gemm<1><<<go, 256, 0, stream>>>(ab, WoT + (size_t)l * 65536, x, x, nullptr, M, DD, 256);
    ln_cast_kernel<<<M, 256, 0, stream>>>(x, ln2_g + l * DD, ln2_b + l * DD, hb);
    mfma_gemm<2><<<gf, 256, 0, stream>>>(hb, W1T + (size_t)l * 262144, nullptr,
                                         ffn, nullptr, M, DFF, 256);
    mfma_gemm<1><<<go, 256, 0, stream>>>(ffn, W2T + (size_t)l * 262144, x, x, nullptr, M, DD, 1024);
  }
  afps_kernel<<<BB, 512, 0, stream>>>(dist, sbuf, idxb);
  pool_ln_kernel<<<BB, 256, 0, stream>>>(x, idxb, gamma, beta, out);
}

// Round 7
// 744.469 us; speedup vs baseline: 5.9971x; 1.1738x over previous
//
#include <hip/hip_runtime.h>
#include <hip/hip_bf16.h>
#include <math.h>

// Problem: B=16, N=512, D=256, H=8, L=4, DFF=1024, K=128, DH=32
#define BB 16
#define NN 512
#define DD 256
#define HH 8
#define LL 4
#define DFF 1024
#define KSEL 128
#define DH 32

typedef __attribute__((ext_vector_type(8))) short bf16x8v;
typedef __attribute__((ext_vector_type(4))) float f32x4v;

// ---------------- workspace layout (byte offsets) ----------------
static const size_t X_B    = 0;
static const size_t QKVB_B = 8388608;
static const size_t VT_B   = 20971520;
static const size_t FFN_B  = 8388608;    // overlays qkvb+Vt (dead during FFN)
static const size_t H_B    = 25165824;
static const size_t ATT_B  = 29360128;
static const size_t WQKV_B = 33554432;
static const size_t WO_B   = 35127296;
static const size_t W1T_B  = 35651584;
static const size_t W2T_B  = 37748736;
static const size_t S_B    = 39845888;
static const size_t MAXD_B = 39878656;   // S_B + 32768
static const size_t IDX_B  = 39878720;   // MAXD_B + 64

// ---------------- helpers ----------------
__device__ __forceinline__ float gelu_f(float x) {
  float x3 = x * x * x;
  return 0.5f * x * (1.f + tanhf(0.7978845608028654f * (x + 0.044715f * x3)));
}

__device__ __forceinline__ short bf16raw(float v) {
  __hip_bfloat16 h = __float2bfloat16(v);
  return *reinterpret_cast<short*>(&h);
}

__device__ __forceinline__ float blk_sum_256(float v, float* stmp) {
  #pragma unroll
  for (int o = 32; o > 0; o >>= 1) v += __shfl_down(v, o, 64);
  if ((threadIdx.x & 63) == 0) stmp[threadIdx.x >> 6] = v;
  __syncthreads();
  if (threadIdx.x == 0) stmp[0] = stmp[0] + stmp[1] + stmp[2] + stmp[3];
  __syncthreads();
  float r = stmp[0];
  __syncthreads();
  return r;
}

// ---------------- kernels ----------------
__global__ void copy_kernel(const float4* __restrict__ src, float4* __restrict__ dst, int n) {
  int i = blockIdx.x * blockDim.x + threadIdx.x;
  if (i < n) dst[i] = src[i];
}

// one-shot: transpose-cast all weights to bf16.
__global__ __launch_bounds__(256) void cast_weights_kernel(
    const float* __restrict__ Wq, const float* __restrict__ Wk,
    const float* __restrict__ Wv, const float* __restrict__ Wo,
    const float* __restrict__ W1, const float* __restrict__ W2,
    __hip_bfloat16* __restrict__ qkvT, __hip_bfloat16* __restrict__ WoT,
    __hip_bfloat16* __restrict__ W1T, __hip_bfloat16* __restrict__ W2T) {
  int i = blockIdx.x * 256 + threadIdx.x;
  if (i < 786432) {                       // qkvT [L][768 n][256 k]
    int l = i / 196608, r = i % 196608;
    int n = r >> 8, k = r & 255;
    const float* src = (n < 256) ? Wq : (n < 512 ? Wk : Wv);
    qkvT[i] = __float2bfloat16(src[l * 65536 + k * 256 + (n & 255)]);
  } else if (i < 1048576) {               // WoT [L][256][256]
    int j = i - 786432;
    int l = j >> 16, r = j & 65535;
    int n = r >> 8, k = r & 255;
    WoT[j] = __float2bfloat16(Wo[l * 65536 + k * 256 + n]);
  } else if (i < 2097152) {               // W1T [L][1024 n][256 k]
    int j = i - 1048576;
    int l = j >> 18, r = j & 262143;
    int n = r >> 8, k = r & 255;
    W1T[j] = __float2bfloat16(W1[l * 262144 + k * 1024 + n]);
  } else {                                // W2T [L][256 n][1024 k]
    int j = i - 2097152;
    int l = j >> 18, r = j & 262143;
    int n = r >> 10, k = r & 1023;
    W2T[j] = __float2bfloat16(W2[l * 262144 + k * 256 + n]);
  }
}

// LayerNorm, writes bf16
__global__ __launch_bounds__(256) void ln_cast_kernel(const float* __restrict__ in,
                                                      const float* __restrict__ g,
                                                      const float* __restrict__ bb,
                                                      __hip_bfloat16* __restrict__ out) {
  __shared__ float stmp[4];
  size_t row = blockIdx.x;
  int d = threadIdx.x;
  float v = in[row * DD + d];
  float mu = blk_sum_256(v, stmp) * (1.0f / DD);
  float diff = v - mu;
  float var = blk_sum_256(diff * diff, stmp) * (1.0f / DD);
  out[row * DD + d] = __float2bfloat16(diff * rsqrtf(var + 1e-6f) * g[d] + bb[d]);
}

// MFMA bf16 GEMM: acc = A[M,K] @ Bt[N,K]^T
// MODE 1: fp32 out = acc + Res; MODE 2: bf16 out = gelu(acc);
// MODE 3: qkv: cols<512 -> bf16 qkvb row-major (pitch 768);
//              cols>=512 -> Vt[b][dim][key] transposed bf16.
template <int MODE>
__global__ __launch_bounds__(256) void mfma_gemm(const __hip_bfloat16* __restrict__ A,
                                                 const __hip_bfloat16* __restrict__ Bt,
                                                 const float* __restrict__ Res,
                                                 void* __restrict__ Cv,
                                                 __hip_bfloat16* __restrict__ Vto,
                                                 int M, int N, int Kd) {
  __shared__ short As[64 * 40];
  __shared__ short Bs[64 * 40];
  const int tid = threadIdx.x;
  const int w = tid >> 6, lane = tid & 63;
  const int m16 = lane & 15, quad = lane >> 4;
  const int bm = blockIdx.y << 6, bn = blockIdx.x << 6;
  const int srow = tid >> 2, scol = (tid & 3) << 3;

  f32x4v zero = {0.f, 0.f, 0.f, 0.f};
  f32x4v acc[4];
  #pragma unroll
  for (int nt = 0; nt < 4; ++nt) acc[nt] = zero;

  const short* Ag = (const short*)A;
  const short* Bg = (const short*)Bt;

  for (int k0 = 0; k0 < Kd; k0 += 32) {
    *(bf16x8v*)&As[srow * 40 + scol] =
        *(const bf16x8v*)(Ag + (size_t)(bm + srow) * Kd + k0 + scol);
    *(bf16x8v*)&Bs[srow * 40 + scol] =
        *(const bf16x8v*)(Bg + (size_t)(bn + srow) * Kd + k0 + scol);
    __syncthreads();
    bf16x8v af = *(bf16x8v*)&As[(w * 16 + m16) * 40 + (quad << 3)];
    #pragma unroll
    for (int nt = 0; nt < 4; ++nt) {
      bf16x8v bf = *(bf16x8v*)&Bs[(nt * 16 + m16) * 40 + (quad << 3)];
      acc[nt] = __builtin_amdgcn_mfma_f32_16x16x32_bf16(af, bf, acc[nt], 0, 0, 0);
    }
    __syncthreads();
  }

  const int erow = bm + w * 16 + quad * 4;
  #pragma unroll
  for (int nt = 0; nt < 4; ++nt) {
    int col = bn + nt * 16 + m16;
    if (MODE == 3) {
      if (col < 512) {
        #pragma unroll
        for (int r = 0; r < 4; ++r)
          ((__hip_bfloat16*)Cv)[(size_t)(erow + r) * 768 + col] =
              __float2bfloat16(acc[nt][r]);
      } else {
        short4 pk;
        pk.x = bf16raw(acc[nt][0]); pk.y = bf16raw(acc[nt][1]);
        pk.z = bf16raw(acc[nt][2]); pk.w = bf16raw(acc[nt][3]);
        int bb2 = erow >> 9, key = erow & 511, dim = col - 512;
        *(short4*)((short*)Vto + (size_t)bb2 * 131072 + (size_t)dim * 512 + key) = pk;
      }
    } else {
      #pragma unroll
      for (int r = 0; r < 4; ++r) {
        float v = acc[nt][r];
        size_t off = (size_t)(erow + r) * N + col;
        if (MODE == 1) ((float*)Cv)[off] = v + Res[off];
        else ((__hip_bfloat16*)Cv)[off] = __float2bfloat16(gelu_f(v));
      }
    }
  }
}

// MFMA flash attention, barrier-free (unchanged from R6).
__global__ __launch_bounds__(512) void attn_kernel(const __hip_bfloat16* __restrict__ qkvb,
                                                   const __hip_bfloat16* __restrict__ vt,
                                                   const float* __restrict__ dist,
                                                   __hip_bfloat16* __restrict__ outg,
                                                   float* __restrict__ s_acc,
                                                   int accum) {
  __shared__ float Pf[8][16 * 36];
  const int tid = threadIdx.x;
  const int h = tid >> 6, lane = tid & 63;
  const int m16 = lane & 15, quad = lane >> 4;
  const int b = blockIdx.y;
  const int qbase = blockIdx.x * 16;
  const float scale = 0.17677669529663687f;
  const f32x4v zero = {0.f, 0.f, 0.f, 0.f};

  const short* qkvs = (const short*)qkvb;
  const short* vts = (const short*)vt + (size_t)b * 131072;
  float* Pw = Pf[h];

  bf16x8v qf = *(const bf16x8v*)(qkvs + ((size_t)(b * NN + qbase + m16)) * 768 + h * 32 + (quad << 3));

  int drow[4];
  #pragma unroll
  for (int r = 0; r < 4; ++r) drow[r] = (b * NN + qbase + quad * 4 + r) * NN;

  f32x4v accO0 = zero, accO1 = zero;
  float lacc[4] = {0.f, 0.f, 0.f, 0.f};

  for (int t0 = 0; t0 < NN; t0 += 32) {
    bf16x8v kf0 = *(const bf16x8v*)(qkvs + ((size_t)(b * NN + t0 + m16)) * 768 + 256 + h * 32 + (quad << 3));
    bf16x8v kf1 = *(const bf16x8v*)(qkvs + ((size_t)(b * NN + t0 + 16 + m16)) * 768 + 256 + h * 32 + (quad << 3));
    f32x4v s0 = __builtin_amdgcn_mfma_f32_16x16x32_bf16(qf, kf0, zero, 0, 0, 0);
    f32x4v s1 = __builtin_amdgcn_mfma_f32_16x16x32_bf16(qf, kf1, zero, 0, 0, 0);
    #pragma unroll
    for (int r = 0; r < 4; ++r) {
      float e0 = __expf(fmaf(s0[r], scale, -dist[drow[r] + t0 + m16]));
      float e1 = __expf(fmaf(s1[r], scale, -dist[drow[r] + t0 + 16 + m16]));
      float t = e0 + e1;
      t += __shfl_xor(t, 1, 64); t += __shfl_xor(t, 2, 64);
      t += __shfl_xor(t, 4, 64); t += __shfl_xor(t, 8, 64);
      lacc[r] += t;
      Pw[(quad * 4 + r) * 36 + m16] = e0;
      Pw[(quad * 4 + r) * 36 + 16 + m16] = e1;
    }
    bf16x8v pfr;
    {
      const float* pr = &Pw[m16 * 36 + (quad << 3)];
      float4 pa = *(const float4*)pr;
      float4 pb = *(const float4*)(pr + 4);
      pfr[0] = bf16raw(pa.x); pfr[1] = bf16raw(pa.y);
      pfr[2] = bf16raw(pa.z); pfr[3] = bf16raw(pa.w);
      pfr[4] = bf16raw(pb.x); pfr[5] = bf16raw(pb.y);
      pfr[6] = bf16raw(pb.z); pfr[7] = bf16raw(pb.w);
    }
    bf16x8v vf0 = *(const bf16x8v*)(vts + (size_t)(h * 32 + m16) * 512 + t0 + (quad << 3));
    bf16x8v vf1 = *(const bf16x8v*)(vts + (size_t)(h * 32 + 16 + m16) * 512 + t0 + (quad << 3));
    accO0 = __builtin_amdgcn_mfma_f32_16x16x32_bf16(pfr, vf0, accO0, 0, 0, 0);
    accO1 = __builtin_amdgcn_mfma_f32_16x16x32_bf16(pfr, vf1, accO1, 0, 0, 0);
  }

  float invl[4];
  #pragma unroll
  for (int r = 0; r < 4; ++r) invl[r] = 1.f / lacc[r];

  #pragma unroll
  for (int r = 0; r < 4; ++r) {
    size_t orow = (size_t)(b * NN + qbase + quad * 4 + r) * DD + h * 32;
    outg[orow + m16] = __float2bfloat16(accO0[r] * invl[r]);
    outg[orow + 16 + m16] = __float2bfloat16(accO1[r] * invl[r]);
  }

  if (accum) {
    for (int t0 = 0; t0 < NN; t0 += 32) {
      bf16x8v kf0 = *(const bf16x8v*)(qkvs + ((size_t)(b * NN + t0 + m16)) * 768 + 256 + h * 32 + (quad << 3));
      bf16x8v kf1 = *(const bf16x8v*)(qkvs + ((size_t)(b * NN + t0 + 16 + m16)) * 768 + 256 + h * 32 + (quad << 3));
      f32x4v s0 = __builtin_amdgcn_mfma_f32_16x16x32_bf16(qf, kf0, zero, 0, 0, 0);
      f32x4v s1 = __builtin_amdgcn_mfma_f32_16x16x32_bf16(qf, kf1, zero, 0, 0, 0);
      float p0 = 0.f, p1 = 0.f;
      #pragma unroll
      for (int r = 0; r < 4; ++r) {
        p0 += __expf(fmaf(s0[r], scale, -dist[drow[r] + t0 + m16])) * invl[r];
        p1 += __expf(fmaf(s1[r], scale, -dist[drow[r] + t0 + 16 + m16])) * invl[r];
      }
      p0 += __shfl_xor(p0, 16, 64); p0 += __shfl_xor(p0, 32, 64);
      p1 += __shfl_xor(p1, 16, 64); p1 += __shfl_xor(p1, 32, 64);
      if (quad == 0) {
        atomicAdd(&s_acc[b * NN + t0 + m16], p0 * 0.125f);
        atomicAdd(&s_acc[b * NN + t0 + 16 + m16], p1 * 0.125f);
      }
    }
  }
}

// parallel max over dist[b] (non-negative) via float-as-uint atomicMax.
// grid (8, B), 256 threads; each thread 32 float4.
__global__ __launch_bounds__(256) void maxd_kernel(const float* __restrict__ dist,
                                                   unsigned int* __restrict__ maxd) {
  const int b = blockIdx.y;
  const int tid = threadIdx.x;
  const float4* p = (const float4*)(dist + (size_t)b * NN * NN) +
                    blockIdx.x * 8192 + tid;
  float m = 0.f;
  #pragma unroll 8
  for (int i = 0; i < 32; ++i) {
    float4 v = p[i * 256];
    m = fmaxf(m, fmaxf(fmaxf(v.x, v.y), fmaxf(v.z, v.w)));
  }
  #pragma unroll
  for (int o = 32; o > 0; o >>= 1) m = fmaxf(m, __shfl_xor(m, o, 64));
  __shared__ float wm[4];
  if ((tid & 63) == 0) wm[tid >> 6] = m;
  __syncthreads();
  if (tid == 0) {
    float mm = fmaxf(fmaxf(wm[0], wm[1]), fmaxf(wm[2], wm[3]));
    atomicMax(&maxd[b], __float_as_uint(mm));
  }
}

// AFPS selection: one wave per batch, barrier-free, registers only.
// Lane owns nodes {r*64+lane : r<8}. dist is symmetric -> column nw == row nw
// (coalesced). Tie-break = smallest index (matches jnp.argmax first-max).
__global__ __launch_bounds__(64) void afps_select_kernel(const float* __restrict__ dist,
                                                         const float* __restrict__ s,
                                                         const unsigned int* __restrict__ maxd,
                                                         int* __restrict__ idx_out) {
  const int b = blockIdx.x;
  const int lane = threadIdx.x;
  const float* db = dist + (size_t)b * NN * NN;

  float sv[8];
  float ms = 0.f;
  #pragma unroll
  for (int r = 0; r < 8; ++r) {
    sv[r] = s[b * NN + r * 64 + lane];
    ms = fmaxf(ms, sv[r]);
  }
  #pragma unroll
  for (int o = 32; o > 0; o >>= 1) ms = fmaxf(ms, __shfl_xor(ms, o, 64));

  const float invmaxd = 1.0f / __uint_as_float(maxd[b]);
  float sn[8], mind[8];
  #pragma unroll
  for (int r = 0; r < 8; ++r) {
    sn[r] = (sv[r] / ms) * 0.1f;
    mind[r] = db[r * 64 + lane] * invmaxd + sn[r];   // row 0 == col 0 (sym)
  }
  unsigned selm = (lane == 0) ? 1u : 0u;  // node 0 selected
  if (lane == 0) idx_out[b * KSEL + 0] = 0;

  for (int it = 1; it < KSEL; ++it) {
    float bestv = -INFINITY;
    int besti = 0x7fffffff;
    #pragma unroll
    for (int r = 0; r < 8; ++r) {
      float v = (selm >> r) & 1u ? -INFINITY : mind[r];
      int idx = r * 64 + lane;
      if (v > bestv || (v == bestv && idx < besti)) { bestv = v; besti = idx; }
    }
    #pragma unroll
    for (int o = 32; o > 0; o >>= 1) {
      float ov = __shfl_xor(bestv, o, 64);
      int oi = __shfl_xor(besti, o, 64);
      if (ov > bestv || (ov == bestv && oi < besti)) { bestv = ov; besti = oi; }
    }
    const int nw = besti;
    if (lane == (nw & 63)) selm |= 1u << (nw >> 6);
    if (lane == 0) idx_out[b * KSEL + it] = nw;
    const float* row = db + (size_t)nw * NN;
    #pragma unroll
    for (int r = 0; r < 8; ++r)
      mind[r] = fminf(mind[r], row[r * 64 + lane] * invmaxd + sn[r]);
  }
}

// one block per batch: gather K rows, mean, LN -> out
__global__ __launch_bounds__(256) void pool_ln_kernel(const float* __restrict__ x,
                                                      const int* __restrict__ idx,
                                                      const float* __restrict__ gamma,
                                                      const float* __restrict__ beta,
                                                      float* __restrict__ out) {
  __shared__ float stmp[4];
  __shared__ int sIdx[KSEL];
  const int b = blockIdx.x;
  const int d = threadIdx.x;
  if (d < KSEL) sIdx[d] = idx[b * KSEL + d];
  __syncthreads();
  float acc = 0.f;
  #pragma unroll 4
  for (int kk = 0; kk < KSEL; ++kk)
    acc += x[((size_t)b * NN + sIdx[kk]) * DD + d];
  float p = acc * (1.0f / KSEL);
  float mu = blk_sum_256(p, stmp) * (1.0f / DD);
  float diff = p - mu;
  float var = blk_sum_256(diff * diff, stmp) * (1.0f / DD);
  out[b * DD + d] = diff * rsqrtf(var + 1e-6f) * gamma[d] + beta[d];
}

// ---------------- launcher ----------------
extern "C" void kernel_launch(void* const* d_in, const int* in_sizes, int n_in,
                              void* d_out, int out_size, void* d_ws, size_t ws_size,
                              hipStream_t stream) {
  (void)in_sizes; (void)n_in; (void)out_size; (void)ws_size;
  const float* x_in  = (const float*)d_in[0];
  const float* dist  = (const float*)d_in[1];
  const float* Wq    = (const float*)d_in[3];
  const float* Wk    = (const float*)d_in[4];
  const float* Wv    = (const float*)d_in[5];
  const float* Wo    = (const float*)d_in[6];
  const float* W1    = (const float*)d_in[7];
  const float* W2    = (const float*)d_in[8];
  const float* ln1_g = (const float*)d_in[9];
  const float* ln1_b = (const float*)d_in[10];
  const float* ln2_g = (const float*)d_in[11];
  const float* ln2_b = (const float*)d_in[12];
  const float* gamma = (const float*)d_in[13];
  const float* beta  = (const float*)d_in[14];

  char* wsb = (char*)d_ws;
  float* x              = (float*)(wsb + X_B);
  __hip_bfloat16* qkvb  = (__hip_bfloat16*)(wsb + QKVB_B);
  __hip_bfloat16* vtb   = (__hip_bfloat16*)(wsb + VT_B);
  __hip_bfloat16* ffn   = (__hip_bfloat16*)(wsb + FFN_B);
  __hip_bfloat16* hb    = (__hip_bfloat16*)(wsb + H_B);
  __hip_bfloat16* ab    = (__hip_bfloat16*)(wsb + ATT_B);
  __hip_bfloat16* WqkvT = (__hip_bfloat16*)(wsb + WQKV_B);
  __hip_bfloat16* WoT   = (__hip_bfloat16*)(wsb + WO_B);
  __hip_bfloat16* W1T   = (__hip_bfloat16*)(wsb + W1T_B);
  __hip_bfloat16* W2T   = (__hip_bfloat16*)(wsb + W2T_B);
  float* sbuf = (float*)(wsb + S_B);
  unsigned int* maxdb = (unsigned int*)(wsb + MAXD_B);
  int*   idxb = (int*)(wsb + IDX_B);
  float* out  = (float*)d_out;

  copy_kernel<<<2048, 256, 0, stream>>>((const float4*)x_in, (float4*)x, 524288);
  hipMemsetAsync(sbuf, 0, BB * NN * sizeof(float) + 64, stream);  // sbuf + maxd
  cast_weights_kernel<<<12288, 256, 0, stream>>>(Wq, Wk, Wv, Wo, W1, W2,
                                                 WqkvT, WoT, W1T, W2T);
  maxd_kernel<<<dim3(8, BB), 256, 0, stream>>>(dist, maxdb);

  const int M = BB * NN;  // 8192
  dim3 gqkv(768 / 64, M / 64);   // (12,128)
  dim3 go(DD / 64, M / 64);      // (4,128)
  dim3 gf(DFF / 64, M / 64);     // (16,128)
  dim3 ga(NN / 16, BB);          // (32,16)

  for (int l = 0; l < LL; ++l) {
    ln_cast_kernel<<<M, 256, 0, stream>>>(x, ln1_g + l * DD, ln1_b + l * DD, hb);
    mfma_gemm<3><<<gqkv, 256, 0, stream>>>(hb, WqkvT + (size_t)l * 768 * 256, nullptr,
                                           qkvb, vtb, M, 768, 256);
    attn_kernel<<<ga, 512, 0, stream>>>(qkvb, vtb, dist, ab, sbuf, (l == LL - 1) ? 1 : 0);
    mfma_gemm<1><<<go, 256, 0, stream>>>(ab, WoT + (size_t)l * 65536, x, x, nullptr, M, DD, 256);
    ln_cast_kernel<<<M, 256, 0, stream>>>(x, ln2_g + l * DD, ln2_b + l * DD, hb);
    mfma_gemm<2><<<gf, 256, 0, stream>>>(hb, W1T + (size_t)l * 262144, nullptr,
                                         ffn, nullptr, M, DFF, 256);
    mfma_gemm<1><<<go, 256, 0, stream>>>(ffn, W2T + (size_t)l * 262144, x, x, nullptr, M, DD, 1024);
  }
  afps_select_kernel<<<BB, 64, 0, stream>>>(dist, sbuf, maxdb, idxb);
  pool_ln_kernel<<<BB, 256, 0, stream>>>(x, idxb, gamma, beta, out);
}